// Round 1
// baseline (2758.352 us; speedup 1.0000x reference)
//
#include <hip/hip_runtime.h>
#include <math.h>

#define B_ 2
#define L_ 1024
#define DM 2048
#define DI 4096
#define DS 16
#define DR 128
#define M_ (B_*L_)

__device__ __forceinline__ float softplus_f(float x) {
    return (x > 20.0f) ? x : log1pf(expf(x));
}
__device__ __forceinline__ float silu_f(float x) {
    return x / (1.0f + expf(-x));
}

// C[M,N] = A[M,K] @ W[N,K]^T   (row-major, leading dims lda/ldw/ldc in floats)
// MODE 0: plain store. MODE 1: C = softplus(acc + 2*bias[n])
template<int BM, int BN, int MODE>
__global__ __launch_bounds__(256)
void gemm_nt(const float* __restrict__ A, int lda,
             const float* __restrict__ W, int ldw,
             float* __restrict__ C, int ldc,
             int K, const float* __restrict__ bias) {
    constexpr int BK = 16;
    constexpr int TM = BM / 16;
    constexpr int TN = BN / 16;
    __shared__ float As[BK][BM];
    __shared__ float Ws[BK][BN];
    const int tid = threadIdx.x;
    const int tx = tid & 15;
    const int ty = tid >> 4;
    const int m0 = blockIdx.y * BM;
    const int n0 = blockIdx.x * BN;

    float acc[TM][TN];
#pragma unroll
    for (int i = 0; i < TM; ++i)
#pragma unroll
        for (int j = 0; j < TN; ++j) acc[i][j] = 0.0f;

    for (int kt = 0; kt < K; kt += BK) {
        // stage A tile (BM rows x 16 k), transposed into As[k][m]
        for (int v = tid; v < BM * 4; v += 256) {
            const int row = v >> 2;
            const int kq  = (v & 3) << 2;
            const float4 t = *reinterpret_cast<const float4*>(
                &A[(size_t)(m0 + row) * lda + kt + kq]);
            As[kq + 0][row] = t.x; As[kq + 1][row] = t.y;
            As[kq + 2][row] = t.z; As[kq + 3][row] = t.w;
        }
        // stage W tile (BN rows x 16 k), transposed into Ws[k][n]
        for (int v = tid; v < BN * 4; v += 256) {
            const int row = v >> 2;
            const int kq  = (v & 3) << 2;
            const float4 t = *reinterpret_cast<const float4*>(
                &W[(size_t)(n0 + row) * ldw + kt + kq]);
            Ws[kq + 0][row] = t.x; Ws[kq + 1][row] = t.y;
            Ws[kq + 2][row] = t.z; Ws[kq + 3][row] = t.w;
        }
        __syncthreads();
#pragma unroll
        for (int kk = 0; kk < BK; ++kk) {
            float a[TM], w[TN];
            if constexpr (TM == 8) {
                *reinterpret_cast<float4*>(&a[0]) =
                    *reinterpret_cast<const float4*>(&As[kk][ty * 8]);
                *reinterpret_cast<float4*>(&a[4]) =
                    *reinterpret_cast<const float4*>(&As[kk][ty * 8 + 4]);
            } else {
#pragma unroll
                for (int i = 0; i < TM; ++i) a[i] = As[kk][ty * TM + i];
            }
            if constexpr (TN == 8) {
                *reinterpret_cast<float4*>(&w[0]) =
                    *reinterpret_cast<const float4*>(&Ws[kk][tx * 8]);
                *reinterpret_cast<float4*>(&w[4]) =
                    *reinterpret_cast<const float4*>(&Ws[kk][tx * 8 + 4]);
            } else {
#pragma unroll
                for (int j = 0; j < TN; ++j) w[j] = Ws[kk][tx * TN + j];
            }
#pragma unroll
            for (int i = 0; i < TM; ++i)
#pragma unroll
                for (int j = 0; j < TN; ++j)
                    acc[i][j] = fmaf(a[i], w[j], acc[i][j]);
        }
        __syncthreads();
    }

#pragma unroll
    for (int i = 0; i < TM; ++i) {
        const size_t rowoff = (size_t)(m0 + ty * TM + i) * ldc + n0 + tx * TN;
#pragma unroll
        for (int j = 0; j < TN; ++j) {
            float v = acc[i][j];
            if constexpr (MODE == 1) {
                v = softplus_f(v + 2.0f * bias[n0 + tx * TN + j]);
            }
            C[rowoff + j] = v;
        }
    }
}

// x_silu[b,l,d] = silu( conv_b[d] + sum_k xz[b, l-3+k, d] * conv_w[d,k] )
__global__ __launch_bounds__(256)
void conv_silu_kernel(const float* __restrict__ xz, const float* __restrict__ cw,
                      const float* __restrict__ cb, float* __restrict__ xs) {
    const int idx = blockIdx.x * 256 + threadIdx.x;
    const int d  = idx & (DI - 1);
    const int bl = idx >> 12;            // DI = 4096 = 2^12
    const int l  = bl & (L_ - 1);
    const int b0 = bl - l;               // b*L
    float s = cb[d];
    const float w0 = cw[d * 4 + 0], w1 = cw[d * 4 + 1];
    const float w2 = cw[d * 4 + 2], w3 = cw[d * 4 + 3];
    if (l >= 3) {
        const float* p = xz + (size_t)bl * (2 * DI) + d;
        s += p[-(size_t)3 * 2 * DI] * w0 + p[-(size_t)2 * 2 * DI] * w1
           + p[-(size_t)1 * 2 * DI] * w2 + p[0] * w3;
    } else {
        const float wk[4] = {w0, w1, w2, w3};
#pragma unroll
        for (int k = 0; k < 4; ++k) {
            const int ls = l - 3 + k;
            if (ls >= 0) s += xz[(size_t)(b0 + ls) * (2 * DI) + d] * wk[k];
        }
    }
    xs[idx] = silu_f(s);
}

// Sequential selective scan. One thread per (b, d, n).
// Block = 256 threads = 16 d-channels x 16 states, grid = B * DI/16.
// Reads dt from dtbuf, overwrites dtbuf[b,l,d] with y*z (consumed-then-written).
__global__ __launch_bounds__(256)
void scan_kernel(const float* __restrict__ xz, const float* __restrict__ xs,
                 const float* __restrict__ xdbl, float* __restrict__ dtbuf,
                 const float* __restrict__ alog, const float* __restrict__ Dp) {
    const int tid = threadIdx.x;
    const int n  = tid & 15;
    const int dg = tid >> 4;
    const int b  = blockIdx.x / (DI / 16);
    const int d  = (blockIdx.x % (DI / 16)) * 16 + dg;

    const float Av = -expf(alog[d * DS + n]);
    const float Dv = Dp[d];
    float state = 0.0f;

    const size_t bl0 = (size_t)b * L_;
    for (int l = 0; l < L_; ++l) {
        const size_t bl = bl0 + l;
        const float dt = dtbuf[bl * DI + d];
        const float x  = xs[bl * DI + d];
        const float Bv = xdbl[bl * 160 + 128 + n];
        const float Cv = xdbl[bl * 160 + 144 + n];
        const float dA = expf(dt * Av);
        state = fmaf(dA, state, dt * Bv * x);
        float contrib = state * Cv;
        contrib += __shfl_xor(contrib, 1);
        contrib += __shfl_xor(contrib, 2);
        contrib += __shfl_xor(contrib, 4);
        contrib += __shfl_xor(contrib, 8);
        if (n == 0) {
            const float y = contrib + x * Dv;
            const float z = xz[bl * (2 * DI) + DI + d];
            dtbuf[bl * DI + d] = y * z;   // y_gated, reuses dt storage
        }
    }
}

extern "C" void kernel_launch(void* const* d_in, const int* in_sizes, int n_in,
                              void* d_out, int out_size, void* d_ws, size_t ws_size,
                              hipStream_t stream) {
    const float* hs   = (const float*)d_in[0];
    const float* ipw  = (const float*)d_in[1];
    const float* cw   = (const float*)d_in[2];
    const float* cb   = (const float*)d_in[3];
    const float* xpw  = (const float*)d_in[4];
    const float* dpw  = (const float*)d_in[5];
    const float* dpb  = (const float*)d_in[6];
    const float* alog = (const float*)d_in[7];
    const float* Dp   = (const float*)d_in[8];
    const float* opw  = (const float*)d_in[9];
    float* out = (float*)d_out;

    float* ws    = (float*)d_ws;
    float* xz    = ws;                         // M * 8192
    float* xs    = xz   + (size_t)M_ * 2 * DI; // M * 4096
    float* xdbl  = xs   + (size_t)M_ * DI;     // M * 160
    float* dtbuf = xdbl + (size_t)M_ * 160;    // M * 4096 (dt, then y*z)

    // 1) xz = hs @ in_proj_w^T      (2048 x 8192 x 2048)
    gemm_nt<128, 128, 0><<<dim3(2 * DI / 128, M_ / 128), 256, 0, stream>>>(
        hs, DM, ipw, DM, xz, 2 * DI, DM, nullptr);
    // 2) conv + bias + silu
    conv_silu_kernel<<<(B_ * L_ * DI) / 256, 256, 0, stream>>>(xz, cw, cb, xs);
    // 3) x_dbl = x_silu @ x_proj_w^T   (2048 x 160 x 4096)
    gemm_nt<128, 32, 0><<<dim3(160 / 32, M_ / 128), 256, 0, stream>>>(
        xs, DI, xpw, DI, xdbl, 160, DI, nullptr);
    // 4) dt = softplus(dt_raw @ dt_proj_w^T + 2*dt_proj_b)  (2048 x 4096 x 128)
    gemm_nt<128, 128, 1><<<dim3(DI / 128, M_ / 128), 256, 0, stream>>>(
        xdbl, 160, dpw, DR, dtbuf, DI, DR, dpb);
    // 5) selective scan -> y*z (overwrites dtbuf)
    scan_kernel<<<B_ * (DI / 16), 256, 0, stream>>>(xz, xs, xdbl, dtbuf, alog, Dp);
    // 6) out = y_gated @ out_proj_w^T  (2048 x 2048 x 4096)
    gemm_nt<128, 128, 0><<<dim3(DM / 128, M_ / 128), 256, 0, stream>>>(
        dtbuf, DI, opw, DI, out, DM, DI, nullptr);
}

// Round 2
// 1568.143 us; speedup vs baseline: 1.7590x; 1.7590x over previous
//
#include <hip/hip_runtime.h>
#include <math.h>
#include <stdint.h>

#define B_ 2
#define L_ 1024
#define DM 2048
#define DI 4096
#define DS 16
#define DR 128
#define M_ (B_*L_)

typedef __attribute__((ext_vector_type(8))) __bf16 bf16x8;
typedef __attribute__((ext_vector_type(4))) float f32x4;

__device__ __forceinline__ float softplus_f(float x) {
    return (x > 20.0f) ? x : log1pf(expf(x));
}
__device__ __forceinline__ float silu_f(float x) {
    return x / (1.0f + expf(-x));
}
__device__ __forceinline__ short f2bf_rn(float x) {
    uint32_t u = __builtin_bit_cast(uint32_t, x);
    u += 0x7FFFu + ((u >> 16) & 1u);
    return (short)(u >> 16);
}
__device__ __forceinline__ float bf2f(short h) {
    uint32_t u = ((uint32_t)(unsigned short)h) << 16;
    return __builtin_bit_cast(float, u);
}
__device__ __forceinline__ void gload16(const void* g, void* l) {
    __builtin_amdgcn_global_load_lds(
        (const __attribute__((address_space(1))) void*)g,
        (__attribute__((address_space(3))) void*)l, 16, 0, 0);
}

// split fp32 -> (hi, lo) bf16 pair, 4 elements/thread
__global__ __launch_bounds__(256)
void split_bf16_kernel(const float* __restrict__ in, short* __restrict__ hi,
                       short* __restrict__ lo, int n4) {
    const int i = blockIdx.x * 256 + threadIdx.x;
    if (i >= n4) return;
    const float4 v = reinterpret_cast<const float4*>(in)[i];
    short4 h, l;
    h.x = f2bf_rn(v.x); l.x = f2bf_rn(v.x - bf2f(h.x));
    h.y = f2bf_rn(v.y); l.y = f2bf_rn(v.y - bf2f(h.y));
    h.z = f2bf_rn(v.z); l.z = f2bf_rn(v.z - bf2f(h.z));
    h.w = f2bf_rn(v.w); l.w = f2bf_rn(v.w - bf2f(h.w));
    reinterpret_cast<short4*>(hi)[i] = h;
    reinterpret_cast<short4*>(lo)[i] = l;
}

// Split-bf16 MFMA GEMM: C[M][N] (fp32) = A[M][K] @ W[N][K]^T, fp32-quality via
// Ahi*Bhi + Ahi*Blo + Alo*Bhi. m97 structure: BMxBN tile, 4 waves (2x2),
// BK=32, global_load_lds staging, 16x16x32 bf16 MFMA.
template<int BM, int BN>
__global__ __launch_bounds__(256)
void gemm_mfma_split(const short* __restrict__ Ahi, const short* __restrict__ Alo,
                     const short* __restrict__ Bhi, const short* __restrict__ Blo,
                     float* __restrict__ C, int M, int N, int K) {
    constexpr int BK = 32;
    constexpr int FM = BM / 32;   // frags per wave (wave covers BM/2 rows)
    constexpr int FN = BN / 32;
    __shared__ alignas(16) short sA[2][BM * BK];
    __shared__ alignas(16) short sB[2][BN * BK];

    const int tid  = threadIdx.x;
    const int wave = tid >> 6;
    const int lane = tid & 63;
    const int wm = wave >> 1, wn = wave & 1;
    const int m0 = blockIdx.y * BM;
    const int n0 = blockIdx.x * BN;
    const int frow = lane & 15;
    const int kg   = lane >> 4;

    f32x4 acc[FM][FN];
#pragma unroll
    for (int mi = 0; mi < FM; ++mi)
#pragma unroll
        for (int ni = 0; ni < FN; ++ni) acc[mi][ni] = (f32x4){0.f, 0.f, 0.f, 0.f};

    for (int kt = 0; kt < K; kt += BK) {
        // stage: each 16B chunk li covers row li/4, k-chunk (li%4)*8
#pragma unroll
        for (int r = 0; r < BM / 64; ++r) {
            const int li = r * 256 + tid;
            const int row = li >> 2, kc = (li & 3) << 3;
            const size_t goff = (size_t)(m0 + row) * K + kt + kc;
            gload16(Ahi + goff, &sA[0][li << 3]);
            gload16(Alo + goff, &sA[1][li << 3]);
        }
#pragma unroll
        for (int r = 0; r < BN / 64; ++r) {
            const int li = r * 256 + tid;
            const int row = li >> 2, kc = (li & 3) << 3;
            const size_t goff = (size_t)(n0 + row) * K + kt + kc;
            gload16(Bhi + goff, &sB[0][li << 3]);
            gload16(Blo + goff, &sB[1][li << 3]);
        }
        __syncthreads();   // drains vmcnt(0): tiles ready

        bf16x8 ah[FM], al[FM], bh[FN], bl[FN];
#pragma unroll
        for (int mi = 0; mi < FM; ++mi) {
            const int idx = (wm * (BM / 2) + mi * 16 + frow) * BK + kg * 8;
            ah[mi] = *reinterpret_cast<const bf16x8*>(&sA[0][idx]);
            al[mi] = *reinterpret_cast<const bf16x8*>(&sA[1][idx]);
        }
#pragma unroll
        for (int ni = 0; ni < FN; ++ni) {
            const int idx = (wn * (BN / 2) + ni * 16 + frow) * BK + kg * 8;
            bh[ni] = *reinterpret_cast<const bf16x8*>(&sB[0][idx]);
            bl[ni] = *reinterpret_cast<const bf16x8*>(&sB[1][idx]);
        }
#pragma unroll
        for (int mi = 0; mi < FM; ++mi)
#pragma unroll
            for (int ni = 0; ni < FN; ++ni) {
                acc[mi][ni] = __builtin_amdgcn_mfma_f32_16x16x32_bf16(ah[mi], bh[ni], acc[mi][ni], 0, 0, 0);
                acc[mi][ni] = __builtin_amdgcn_mfma_f32_16x16x32_bf16(ah[mi], bl[ni], acc[mi][ni], 0, 0, 0);
                acc[mi][ni] = __builtin_amdgcn_mfma_f32_16x16x32_bf16(al[mi], bh[ni], acc[mi][ni], 0, 0, 0);
            }
        __syncthreads();   // protect LDS before next stage
    }

    const int crow0 = m0 + wm * (BM / 2) + (lane >> 4) * 4;
    const int ccol0 = n0 + wn * (BN / 2) + (lane & 15);
#pragma unroll
    for (int mi = 0; mi < FM; ++mi)
#pragma unroll
        for (int ni = 0; ni < FN; ++ni)
#pragma unroll
            for (int r = 0; r < 4; ++r)
                C[(size_t)(crow0 + mi * 16 + r) * N + ccol0 + ni * 16] = acc[mi][ni][r];
}

// C[M,N] = A[M,K] @ W[N,K]^T  fp32 vector GEMM (for the small projections)
// MODE 0: plain store. MODE 1: C = softplus(acc + 2*bias[n])
template<int BM, int BN, int MODE>
__global__ __launch_bounds__(256)
void gemm_nt(const float* __restrict__ A, int lda,
             const float* __restrict__ W, int ldw,
             float* __restrict__ C, int ldc,
             int K, const float* __restrict__ bias) {
    constexpr int BK = 16;
    constexpr int TM = BM / 16;
    constexpr int TN = BN / 16;
    __shared__ float As[BK][BM];
    __shared__ float Ws[BK][BN];
    const int tid = threadIdx.x;
    const int tx = tid & 15;
    const int ty = tid >> 4;
    const int m0 = blockIdx.y * BM;
    const int n0 = blockIdx.x * BN;

    float acc[TM][TN];
#pragma unroll
    for (int i = 0; i < TM; ++i)
#pragma unroll
        for (int j = 0; j < TN; ++j) acc[i][j] = 0.0f;

    for (int kt = 0; kt < K; kt += BK) {
        for (int v = tid; v < BM * 4; v += 256) {
            const int row = v >> 2;
            const int kq  = (v & 3) << 2;
            const float4 t = *reinterpret_cast<const float4*>(
                &A[(size_t)(m0 + row) * lda + kt + kq]);
            As[kq + 0][row] = t.x; As[kq + 1][row] = t.y;
            As[kq + 2][row] = t.z; As[kq + 3][row] = t.w;
        }
        for (int v = tid; v < BN * 4; v += 256) {
            const int row = v >> 2;
            const int kq  = (v & 3) << 2;
            const float4 t = *reinterpret_cast<const float4*>(
                &W[(size_t)(n0 + row) * ldw + kt + kq]);
            Ws[kq + 0][row] = t.x; Ws[kq + 1][row] = t.y;
            Ws[kq + 2][row] = t.z; Ws[kq + 3][row] = t.w;
        }
        __syncthreads();
#pragma unroll
        for (int kk = 0; kk < BK; ++kk) {
            float a[TM], w[TN];
#pragma unroll
            for (int i = 0; i < TM; ++i) a[i] = As[kk][ty * TM + i];
#pragma unroll
            for (int j = 0; j < TN; ++j) w[j] = Ws[kk][tx * TN + j];
#pragma unroll
            for (int i = 0; i < TM; ++i)
#pragma unroll
                for (int j = 0; j < TN; ++j)
                    acc[i][j] = fmaf(a[i], w[j], acc[i][j]);
        }
        __syncthreads();
    }

#pragma unroll
    for (int i = 0; i < TM; ++i) {
        const size_t rowoff = (size_t)(m0 + ty * TM + i) * ldc + n0 + tx * TN;
#pragma unroll
        for (int j = 0; j < TN; ++j) {
            float v = acc[i][j];
            if constexpr (MODE == 1) {
                v = softplus_f(v + 2.0f * bias[n0 + tx * TN + j]);
            }
            C[rowoff + j] = v;
        }
    }
}

// x_silu[b,l,d] = silu( conv_b[d] + sum_k xz[b, l-3+k, d] * conv_w[d,k] )
__global__ __launch_bounds__(256)
void conv_silu_kernel(const float* __restrict__ xz, const float* __restrict__ cw,
                      const float* __restrict__ cb, float* __restrict__ xs) {
    const int idx = blockIdx.x * 256 + threadIdx.x;
    const int d  = idx & (DI - 1);
    const int bl = idx >> 12;
    const int l  = bl & (L_ - 1);
    const int b0 = bl - l;
    float s = cb[d];
    const float w0 = cw[d * 4 + 0], w1 = cw[d * 4 + 1];
    const float w2 = cw[d * 4 + 2], w3 = cw[d * 4 + 3];
    if (l >= 3) {
        const float* p = xz + (size_t)bl * (2 * DI) + d;
        s += p[-(size_t)3 * 2 * DI] * w0 + p[-(size_t)2 * 2 * DI] * w1
           + p[-(size_t)1 * 2 * DI] * w2 + p[0] * w3;
    } else {
        const float wk[4] = {w0, w1, w2, w3};
#pragma unroll
        for (int k = 0; k < 4; ++k) {
            const int ls = l - 3 + k;
            if (ls >= 0) s += xz[(size_t)(b0 + ls) * (2 * DI) + d] * wk[k];
        }
    }
    xs[idx] = silu_f(s);
}

// Sequential selective scan. Block = 16 d-channels x 16 states.
__global__ __launch_bounds__(256)
void scan_kernel(const float* __restrict__ xz, const float* __restrict__ xs,
                 const float* __restrict__ xdbl, float* __restrict__ dtbuf,
                 const float* __restrict__ alog, const float* __restrict__ Dp) {
    const int tid = threadIdx.x;
    const int n  = tid & 15;
    const int dg = tid >> 4;
    const int b  = blockIdx.x / (DI / 16);
    const int d  = (blockIdx.x % (DI / 16)) * 16 + dg;

    const float Av = -expf(alog[d * DS + n]);
    const float Dv = Dp[d];
    float state = 0.0f;

    const size_t bl0 = (size_t)b * L_;
    for (int l = 0; l < L_; ++l) {
        const size_t bl = bl0 + l;
        const float dt = dtbuf[bl * DI + d];
        const float x  = xs[bl * DI + d];
        const float Bv = xdbl[bl * 160 + 128 + n];
        const float Cv = xdbl[bl * 160 + 144 + n];
        const float dA = expf(dt * Av);
        state = fmaf(dA, state, dt * Bv * x);
        float contrib = state * Cv;
        contrib += __shfl_xor(contrib, 1);
        contrib += __shfl_xor(contrib, 2);
        contrib += __shfl_xor(contrib, 4);
        contrib += __shfl_xor(contrib, 8);
        if (n == 0) {
            const float y = contrib + x * Dv;
            const float z = xz[bl * (2 * DI) + DI + d];
            dtbuf[bl * DI + d] = y * z;   // y_gated, reuses dt storage
        }
    }
}

extern "C" void kernel_launch(void* const* d_in, const int* in_sizes, int n_in,
                              void* d_out, int out_size, void* d_ws, size_t ws_size,
                              hipStream_t stream) {
    const float* hs   = (const float*)d_in[0];
    const float* ipw  = (const float*)d_in[1];
    const float* cw   = (const float*)d_in[2];
    const float* cb   = (const float*)d_in[3];
    const float* xpw  = (const float*)d_in[4];
    const float* dpw  = (const float*)d_in[5];
    const float* dpb  = (const float*)d_in[6];
    const float* alog = (const float*)d_in[7];
    const float* Dp   = (const float*)d_in[8];
    const float* opw  = (const float*)d_in[9];
    float* out = (float*)d_out;

    float* ws    = (float*)d_ws;
    float* xz    = ws;                         // 16,777,216 f
    float* xs    = xz   + (size_t)M_ * 2 * DI; // 8,388,608 f
    float* xdbl  = xs   + (size_t)M_ * DI;     // 327,680 f
    float* dtbuf = xdbl + (size_t)M_ * 160;    // 8,388,608 f
    short* bfb   = (short*)(dtbuf + (size_t)M_ * DI);
    // phase 1 (GEMM1 operands)
    short* hs_hi  = bfb;
    short* hs_lo  = hs_hi + (size_t)M_ * DM;
    short* ipw_hi = hs_lo + (size_t)M_ * DM;
    short* ipw_lo = ipw_hi + (size_t)2 * DI * DM;
    // phase 2 (GEMM6 operands) — aliases phase 1 region
    short* yg_hi  = bfb;
    short* yg_lo  = yg_hi + (size_t)M_ * DI;
    short* opw_hi = yg_lo + (size_t)M_ * DI;
    short* opw_lo = opw_hi + (size_t)DM * DI;

    // --- split GEMM1 operands to bf16 hi/lo ---
    split_bf16_kernel<<<(M_ * DM / 4 + 255) / 256, 256, 0, stream>>>(hs, hs_hi, hs_lo, M_ * DM / 4);
    split_bf16_kernel<<<(2 * DI * DM / 4 + 255) / 256, 256, 0, stream>>>(ipw, ipw_hi, ipw_lo, 2 * DI * DM / 4);

    // 1) xz = hs @ in_proj_w^T      (2048 x 8192 x 2048), MFMA split-bf16
    gemm_mfma_split<128, 128><<<dim3(2 * DI / 128, M_ / 128), 256, 0, stream>>>(
        hs_hi, hs_lo, ipw_hi, ipw_lo, xz, M_, 2 * DI, DM);
    // 2) conv + bias + silu
    conv_silu_kernel<<<(B_ * L_ * DI) / 256, 256, 0, stream>>>(xz, cw, cb, xs);
    // 3) x_dbl = x_silu @ x_proj_w^T   (2048 x 160 x 4096)
    gemm_nt<128, 32, 0><<<dim3(160 / 32, M_ / 128), 256, 0, stream>>>(
        xs, DI, xpw, DI, xdbl, 160, DI, nullptr);
    // 4) dt = softplus(dt_raw @ dt_proj_w^T + 2*dt_proj_b)  (2048 x 4096 x 128)
    gemm_nt<128, 128, 1><<<dim3(DI / 128, M_ / 128), 256, 0, stream>>>(
        xdbl, 160, dpw, DR, dtbuf, DI, DR, dpb);
    // 5) selective scan -> y*z (overwrites dtbuf)
    scan_kernel<<<B_ * (DI / 16), 256, 0, stream>>>(xz, xs, xdbl, dtbuf, alog, Dp);
    // --- split GEMM6 operands ---
    split_bf16_kernel<<<(M_ * DI / 4 + 255) / 256, 256, 0, stream>>>(dtbuf, yg_hi, yg_lo, M_ * DI / 4);
    split_bf16_kernel<<<(DM * DI / 4 + 255) / 256, 256, 0, stream>>>(opw, opw_hi, opw_lo, DM * DI / 4);
    // 6) out = y_gated @ out_proj_w^T  (2048 x 2048 x 4096), MFMA split-bf16
    gemm_mfma_split<128, 64><<<dim3(DM / 64, M_ / 128), 256, 0, stream>>>(
        yg_hi, yg_lo, opw_hi, opw_lo, out, M_, DM, DI);
}

// Round 3
// 1135.433 us; speedup vs baseline: 2.4293x; 1.3811x over previous
//
#include <hip/hip_runtime.h>
#include <math.h>
#include <stdint.h>

#define B_ 2
#define L_ 1024
#define DM 2048
#define DI 4096
#define DS 16
#define DR 128
#define M_ (B_*L_)
#define NCH 16          // chunks per sequence
#define LC  64          // chunk length
#define NCHAIN (B_*DI*DS)   // 131072 scan chains

typedef __attribute__((ext_vector_type(8))) __bf16 bf16x8;
typedef __attribute__((ext_vector_type(4))) float f32x4;

__device__ __forceinline__ float softplus_f(float x) {
    return (x > 20.0f) ? x : log1pf(expf(x));
}
__device__ __forceinline__ float silu_f(float x) {
    return x / (1.0f + expf(-x));
}
__device__ __forceinline__ short f2bf_rn(float x) {
    uint32_t u = __builtin_bit_cast(uint32_t, x);
    u += 0x7FFFu + ((u >> 16) & 1u);
    return (short)(u >> 16);
}
__device__ __forceinline__ float bf2f(short h) {
    uint32_t u = ((uint32_t)(unsigned short)h) << 16;
    return __builtin_bit_cast(float, u);
}
__device__ __forceinline__ void gload16(const void* g, void* l) {
    __builtin_amdgcn_global_load_lds(
        (const __attribute__((address_space(1))) void*)g,
        (__attribute__((address_space(3))) void*)l, 16, 0, 0);
}

// ---------------- bf16 split kernels ----------------
__global__ __launch_bounds__(256)
void split_bf16_kernel(const float* __restrict__ in, short* __restrict__ hi,
                       short* __restrict__ lo, int n4) {
    const int i = blockIdx.x * 256 + threadIdx.x;
    if (i >= n4) return;
    const float4 v = reinterpret_cast<const float4*>(in)[i];
    short4 h, l;
    h.x = f2bf_rn(v.x); l.x = f2bf_rn(v.x - bf2f(h.x));
    h.y = f2bf_rn(v.y); l.y = f2bf_rn(v.y - bf2f(h.y));
    h.z = f2bf_rn(v.z); l.z = f2bf_rn(v.z - bf2f(h.z));
    h.w = f2bf_rn(v.w); l.w = f2bf_rn(v.w - bf2f(h.w));
    reinterpret_cast<short4*>(hi)[i] = h;
    reinterpret_cast<short4*>(lo)[i] = l;
}

// split with z-gating: val = y[i] * z[i] where z lives in xz's second half
__global__ __launch_bounds__(256)
void split_gate_kernel(const float* __restrict__ y, const float* __restrict__ xz,
                       short* __restrict__ hi, short* __restrict__ lo) {
    const int i = blockIdx.x * 256 + threadIdx.x;     // over M_*DI/4
    const int d4 = i & (DI / 4 - 1);
    const int bl = i >> 10;
    const float4 yv = reinterpret_cast<const float4*>(y)[i];
    const float4 zv = *reinterpret_cast<const float4*>(
        &xz[(size_t)bl * 2 * DI + DI + d4 * 4]);
    float4 v;
    v.x = yv.x * zv.x; v.y = yv.y * zv.y; v.z = yv.z * zv.z; v.w = yv.w * zv.w;
    short4 h, l;
    h.x = f2bf_rn(v.x); l.x = f2bf_rn(v.x - bf2f(h.x));
    h.y = f2bf_rn(v.y); l.y = f2bf_rn(v.y - bf2f(h.y));
    h.z = f2bf_rn(v.z); l.z = f2bf_rn(v.z - bf2f(h.z));
    h.w = f2bf_rn(v.w); l.w = f2bf_rn(v.w - bf2f(h.w));
    reinterpret_cast<short4*>(hi)[i] = h;
    reinterpret_cast<short4*>(lo)[i] = l;
}

// ---------------- MFMA split-bf16 GEMM (m97 structure) ----------------
template<int BM, int BN>
__global__ __launch_bounds__(256)
void gemm_mfma_split(const short* __restrict__ Ahi, const short* __restrict__ Alo,
                     const short* __restrict__ Bhi, const short* __restrict__ Blo,
                     float* __restrict__ C, int M, int N, int K) {
    constexpr int BK = 32;
    constexpr int FM = BM / 32;
    constexpr int FN = BN / 32;
    __shared__ alignas(16) short sA[2][BM * BK];
    __shared__ alignas(16) short sB[2][BN * BK];

    const int tid  = threadIdx.x;
    const int wave = tid >> 6;
    const int lane = tid & 63;
    const int wm = wave >> 1, wn = wave & 1;
    const int m0 = blockIdx.y * BM;
    const int n0 = blockIdx.x * BN;
    const int frow = lane & 15;
    const int kg   = lane >> 4;

    f32x4 acc[FM][FN];
#pragma unroll
    for (int mi = 0; mi < FM; ++mi)
#pragma unroll
        for (int ni = 0; ni < FN; ++ni) acc[mi][ni] = (f32x4){0.f, 0.f, 0.f, 0.f};

    for (int kt = 0; kt < K; kt += BK) {
#pragma unroll
        for (int r = 0; r < BM / 64; ++r) {
            const int li = r * 256 + tid;
            const int row = li >> 2, kc = (li & 3) << 3;
            const size_t goff = (size_t)(m0 + row) * K + kt + kc;
            gload16(Ahi + goff, &sA[0][li << 3]);
            gload16(Alo + goff, &sA[1][li << 3]);
        }
#pragma unroll
        for (int r = 0; r < BN / 64; ++r) {
            const int li = r * 256 + tid;
            const int row = li >> 2, kc = (li & 3) << 3;
            const size_t goff = (size_t)(n0 + row) * K + kt + kc;
            gload16(Bhi + goff, &sB[0][li << 3]);
            gload16(Blo + goff, &sB[1][li << 3]);
        }
        __syncthreads();

        bf16x8 ah[FM], al[FM], bh[FN], bl[FN];
#pragma unroll
        for (int mi = 0; mi < FM; ++mi) {
            const int idx = (wm * (BM / 2) + mi * 16 + frow) * BK + kg * 8;
            ah[mi] = *reinterpret_cast<const bf16x8*>(&sA[0][idx]);
            al[mi] = *reinterpret_cast<const bf16x8*>(&sA[1][idx]);
        }
#pragma unroll
        for (int ni = 0; ni < FN; ++ni) {
            const int idx = (wn * (BN / 2) + ni * 16 + frow) * BK + kg * 8;
            bh[ni] = *reinterpret_cast<const bf16x8*>(&sB[0][idx]);
            bl[ni] = *reinterpret_cast<const bf16x8*>(&sB[1][idx]);
        }
#pragma unroll
        for (int mi = 0; mi < FM; ++mi)
#pragma unroll
            for (int ni = 0; ni < FN; ++ni) {
                acc[mi][ni] = __builtin_amdgcn_mfma_f32_16x16x32_bf16(ah[mi], bh[ni], acc[mi][ni], 0, 0, 0);
                acc[mi][ni] = __builtin_amdgcn_mfma_f32_16x16x32_bf16(ah[mi], bl[ni], acc[mi][ni], 0, 0, 0);
                acc[mi][ni] = __builtin_amdgcn_mfma_f32_16x16x32_bf16(al[mi], bh[ni], acc[mi][ni], 0, 0, 0);
            }
        __syncthreads();
    }

    const int crow0 = m0 + wm * (BM / 2) + (lane >> 4) * 4;
    const int ccol0 = n0 + wn * (BN / 2) + (lane & 15);
#pragma unroll
    for (int mi = 0; mi < FM; ++mi)
#pragma unroll
        for (int ni = 0; ni < FN; ++ni)
#pragma unroll
            for (int r = 0; r < 4; ++r)
                C[(size_t)(crow0 + mi * 16 + r) * N + ccol0 + ni * 16] = acc[mi][ni][r];
}

// ---------------- fp32 vector GEMM (small projections) ----------------
template<int BM, int BN, int MODE>
__global__ __launch_bounds__(256)
void gemm_nt(const float* __restrict__ A, int lda,
             const float* __restrict__ W, int ldw,
             float* __restrict__ C, int ldc,
             int K, const float* __restrict__ bias) {
    constexpr int BK = 16;
    constexpr int TM = BM / 16;
    constexpr int TN = BN / 16;
    __shared__ float As[BK][BM];
    __shared__ float Ws[BK][BN];
    const int tid = threadIdx.x;
    const int tx = tid & 15;
    const int ty = tid >> 4;
    const int m0 = blockIdx.y * BM;
    const int n0 = blockIdx.x * BN;

    float acc[TM][TN];
#pragma unroll
    for (int i = 0; i < TM; ++i)
#pragma unroll
        for (int j = 0; j < TN; ++j) acc[i][j] = 0.0f;

    for (int kt = 0; kt < K; kt += BK) {
        for (int v = tid; v < BM * 4; v += 256) {
            const int row = v >> 2;
            const int kq  = (v & 3) << 2;
            const float4 t = *reinterpret_cast<const float4*>(
                &A[(size_t)(m0 + row) * lda + kt + kq]);
            As[kq + 0][row] = t.x; As[kq + 1][row] = t.y;
            As[kq + 2][row] = t.z; As[kq + 3][row] = t.w;
        }
        for (int v = tid; v < BN * 4; v += 256) {
            const int row = v >> 2;
            const int kq  = (v & 3) << 2;
            const float4 t = *reinterpret_cast<const float4*>(
                &W[(size_t)(n0 + row) * ldw + kt + kq]);
            Ws[kq + 0][row] = t.x; Ws[kq + 1][row] = t.y;
            Ws[kq + 2][row] = t.z; Ws[kq + 3][row] = t.w;
        }
        __syncthreads();
#pragma unroll
        for (int kk = 0; kk < BK; ++kk) {
            float a[TM], w[TN];
#pragma unroll
            for (int i = 0; i < TM; ++i) a[i] = As[kk][ty * TM + i];
#pragma unroll
            for (int j = 0; j < TN; ++j) w[j] = Ws[kk][tx * TN + j];
#pragma unroll
            for (int i = 0; i < TM; ++i)
#pragma unroll
                for (int j = 0; j < TN; ++j)
                    acc[i][j] = fmaf(a[i], w[j], acc[i][j]);
        }
        __syncthreads();
    }

#pragma unroll
    for (int i = 0; i < TM; ++i) {
        const size_t rowoff = (size_t)(m0 + ty * TM + i) * ldc + n0 + tx * TN;
#pragma unroll
        for (int j = 0; j < TN; ++j) {
            float v = acc[i][j];
            if constexpr (MODE == 1) {
                v = softplus_f(v + 2.0f * bias[n0 + tx * TN + j]);
            }
            C[rowoff + j] = v;
        }
    }
}

// ---------------- conv + bias + silu ----------------
__global__ __launch_bounds__(256)
void conv_silu_kernel(const float* __restrict__ xz, const float* __restrict__ cw,
                      const float* __restrict__ cb, float* __restrict__ xs) {
    const int idx = blockIdx.x * 256 + threadIdx.x;
    const int d  = idx & (DI - 1);
    const int bl = idx >> 12;
    const int l  = bl & (L_ - 1);
    const int b0 = bl - l;
    float s = cb[d];
    const float w0 = cw[d * 4 + 0], w1 = cw[d * 4 + 1];
    const float w2 = cw[d * 4 + 2], w3 = cw[d * 4 + 3];
    if (l >= 3) {
        const float* p = xz + (size_t)bl * (2 * DI) + d;
        s += p[-(size_t)3 * 2 * DI] * w0 + p[-(size_t)2 * 2 * DI] * w1
           + p[-(size_t)1 * 2 * DI] * w2 + p[0] * w3;
    } else {
        const float wk[4] = {w0, w1, w2, w3};
#pragma unroll
        for (int k = 0; k < 4; ++k) {
            const int ls = l - 3 + k;
            if (ls >= 0) s += xz[(size_t)(b0 + ls) * (2 * DI) + d] * wk[k];
        }
    }
    xs[idx] = silu_f(s);
}

// ---------------- tiled transpose [M_][DI] -> [DI][M_] ----------------
__global__ __launch_bounds__(256)
void transpose_kernel(const float* __restrict__ src, float* __restrict__ dst) {
    __shared__ float tile[32][33];
    const int bx = blockIdx.x;            // DI/32 tiles
    const int by = blockIdx.y;            // M_/32 tiles
    const int tx = threadIdx.x & 31;
    const int ty = threadIdx.x >> 5;      // 0..7
#pragma unroll
    for (int r = 0; r < 32; r += 8)
        tile[ty + r][tx] = src[(size_t)(by * 32 + ty + r) * DI + bx * 32 + tx];
    __syncthreads();
#pragma unroll
    for (int r = 0; r < 32; r += 8)
        dst[(size_t)(bx * 32 + ty + r) * M_ + by * 32 + tx] = tile[tx][ty + r];
}

// ---------------- B/C transpose: xdbl[bl][160] -> Bt/Ct [n][bl] ----------------
__global__ __launch_bounds__(256)
void bc_transpose_kernel(const float* __restrict__ xdbl,
                         float* __restrict__ Bt, float* __restrict__ Ct) {
    const int idx = blockIdx.x * 256 + threadIdx.x;   // over DS*M_
    const int bl = idx & (M_ - 1);
    const int n  = idx >> 11;
    Bt[idx] = xdbl[(size_t)bl * 160 + 128 + n];
    Ct[idx] = xdbl[(size_t)bl * 160 + 144 + n];
}

// ---------------- scan phase 1: chunk-local summaries ----------------
// grid: b(2) x dblk(256) x chunk(16) = 8192 blocks; block: 16 d x 16 n
// summaries layout [c][b*DI*16 + d*16 + n]  (coalesced everywhere)
__global__ __launch_bounds__(256)
void scan_phase1(const float* __restrict__ dt_t, const float* __restrict__ xs_t,
                 const float* __restrict__ Bt, const float* __restrict__ alog,
                 float* __restrict__ sfin, float* __restrict__ aprod) {
    const int c    = blockIdx.x & 15;
    const int dblk = (blockIdx.x >> 4) & 255;
    const int b    = blockIdx.x >> 12;
    const int tid  = threadIdx.x;
    const int n  = tid & 15;
    const int dg = tid >> 4;
    const int d  = dblk * 16 + dg;

    const float Av = -expf(alog[d * DS + n]);
    const size_t rowoff = (size_t)d * M_ + b * L_ + c * LC;
    const float* dtp = dt_t + rowoff;
    const float* xsp = xs_t + rowoff;
    const float* Bp  = Bt + (size_t)n * M_ + b * L_ + c * LC;

    float s = 0.f, dts = 0.f;
#pragma unroll 4
    for (int l = 0; l < LC; l += 4) {
        const float4 dt4 = *reinterpret_cast<const float4*>(dtp + l);
        const float4 x4  = *reinterpret_cast<const float4*>(xsp + l);
        const float4 b4  = *reinterpret_cast<const float4*>(Bp + l);
        s = fmaf(__expf(dt4.x * Av), s, dt4.x * b4.x * x4.x); dts += dt4.x;
        s = fmaf(__expf(dt4.y * Av), s, dt4.y * b4.y * x4.y); dts += dt4.y;
        s = fmaf(__expf(dt4.z * Av), s, dt4.z * b4.z * x4.z); dts += dt4.z;
        s = fmaf(__expf(dt4.w * Av), s, dt4.w * b4.w * x4.w); dts += dt4.w;
    }
    const size_t o = (size_t)c * NCHAIN + ((size_t)(b * DI + d)) * DS + n;
    sfin[o]  = s;
    aprod[o] = __expf(Av * dts);
}

// ---------------- scan phase 2: cross-chunk prefix ----------------
__global__ __launch_bounds__(256)
void scan_phase2(const float* __restrict__ sfin, const float* __restrict__ aprod,
                 float* __restrict__ prefix) {
    const int t = blockIdx.x * 256 + threadIdx.x;   // chain id, NCHAIN total
    float p = 0.f;
#pragma unroll
    for (int c = 0; c < NCH; ++c) {
        const size_t o = (size_t)c * NCHAIN + t;
        prefix[o] = p;
        p = fmaf(aprod[o], p, sfin[o]);
    }
}

// ---------------- scan phase 3: finalize + y output ----------------
__global__ __launch_bounds__(256)
void scan_phase3(const float* __restrict__ dt_t, const float* __restrict__ xs_t,
                 const float* __restrict__ Bt, const float* __restrict__ Ct,
                 const float* __restrict__ alog, const float* __restrict__ Dp,
                 const float* __restrict__ prefix, float* __restrict__ ybuf) {
    const int c    = blockIdx.x & 15;
    const int dblk = (blockIdx.x >> 4) & 255;
    const int b    = blockIdx.x >> 12;
    const int tid  = threadIdx.x;
    const int n  = tid & 15;
    const int dg = tid >> 4;
    const int d  = dblk * 16 + dg;

    const float Av = -expf(alog[d * DS + n]);
    const float Dv = Dp[d];
    float s = prefix[(size_t)c * NCHAIN + ((size_t)(b * DI + d)) * DS + n];

    const size_t rowoff = (size_t)d * M_ + b * L_ + c * LC;
    const float* dtp = dt_t + rowoff;
    const float* xsp = xs_t + rowoff;
    const float* Bp  = Bt + (size_t)n * M_ + b * L_ + c * LC;
    const float* Cp  = Ct + (size_t)n * M_ + b * L_ + c * LC;
    float* yout = ybuf + (size_t)(b * L_ + c * LC) * DI + d;

#pragma unroll 2
    for (int l = 0; l < LC; l += 4) {
        const float4 dt4 = *reinterpret_cast<const float4*>(dtp + l);
        const float4 x4  = *reinterpret_cast<const float4*>(xsp + l);
        const float4 b4  = *reinterpret_cast<const float4*>(Bp + l);
        const float4 c4  = *reinterpret_cast<const float4*>(Cp + l);
#pragma unroll
        for (int k = 0; k < 4; ++k) {
            const float dt = (k == 0) ? dt4.x : (k == 1) ? dt4.y : (k == 2) ? dt4.z : dt4.w;
            const float x  = (k == 0) ? x4.x  : (k == 1) ? x4.y  : (k == 2) ? x4.z  : x4.w;
            const float Bv = (k == 0) ? b4.x  : (k == 1) ? b4.y  : (k == 2) ? b4.z  : b4.w;
            const float Cv = (k == 0) ? c4.x  : (k == 1) ? c4.y  : (k == 2) ? c4.z  : c4.w;
            s = fmaf(__expf(dt * Av), s, dt * Bv * x);
            float contrib = s * Cv;
            contrib += __shfl_xor(contrib, 1);
            contrib += __shfl_xor(contrib, 2);
            contrib += __shfl_xor(contrib, 4);
            contrib += __shfl_xor(contrib, 8);
            if (n == 0) yout[(size_t)(l + k) * DI] = fmaf(x, Dv, contrib);
        }
    }
}

extern "C" void kernel_launch(void* const* d_in, const int* in_sizes, int n_in,
                              void* d_out, int out_size, void* d_ws, size_t ws_size,
                              hipStream_t stream) {
    const float* hs   = (const float*)d_in[0];
    const float* ipw  = (const float*)d_in[1];
    const float* cw   = (const float*)d_in[2];
    const float* cb   = (const float*)d_in[3];
    const float* xpw  = (const float*)d_in[4];
    const float* dpw  = (const float*)d_in[5];
    const float* dpb  = (const float*)d_in[6];
    const float* alog = (const float*)d_in[7];
    const float* Dp   = (const float*)d_in[8];
    const float* opw  = (const float*)d_in[9];
    float* out = (float*)d_out;

    float* ws    = (float*)d_ws;
    float* xz    = ws;                              // 16,777,216 f
    float* xs    = xz   + (size_t)16777216;         //  8,388,608 f
    float* xdbl  = xs   + (size_t)8388608;          //    327,680 f
    float* ybuf  = xdbl + (size_t)327680;           //  8,388,608 f (dt, then y)
    float* Bt    = ybuf + (size_t)8388608;          //     32,768 f
    float* Ct    = Bt   + (size_t)32768;            //     32,768 f
    float* R     = Ct   + (size_t)32768;            // shared region

    // R region, scan view
    float* xs_t  = R;                               // 8,388,608 f
    float* dt_t  = R + (size_t)8388608;             // 8,388,608 f
    float* sfin  = R + (size_t)16777216;            // 2,097,152 f
    float* aprd  = sfin + (size_t)2097152;          // 2,097,152 f
    float* pref  = aprd + (size_t)2097152;          // 2,097,152 f
    // R region, phase-1 split view (dead after GEMM1)
    short* hs_hi  = (short*)R;
    short* hs_lo  = hs_hi + (size_t)M_ * DM;
    short* ipw_hi = hs_lo + (size_t)M_ * DM;
    short* ipw_lo = ipw_hi + (size_t)2 * DI * DM;
    // R region, phase-2 split view (written after scan dies)
    short* yg_hi  = (short*)R;
    short* yg_lo  = yg_hi + (size_t)M_ * DI;
    short* opw_hi = yg_lo + (size_t)M_ * DI;
    short* opw_lo = opw_hi + (size_t)DM * DI;

    // 1) xz = hs @ in_proj_w^T  (split-bf16 MFMA)
    split_bf16_kernel<<<(M_ * DM / 4 + 255) / 256, 256, 0, stream>>>(hs, hs_hi, hs_lo, M_ * DM / 4);
    split_bf16_kernel<<<(2 * DI * DM / 4 + 255) / 256, 256, 0, stream>>>(ipw, ipw_hi, ipw_lo, 2 * DI * DM / 4);
    gemm_mfma_split<128, 128><<<dim3(2 * DI / 128, M_ / 128), 256, 0, stream>>>(
        hs_hi, hs_lo, ipw_hi, ipw_lo, xz, M_, 2 * DI, DM);

    // 2) conv + silu
    conv_silu_kernel<<<(B_ * L_ * DI) / 256, 256, 0, stream>>>(xz, cw, cb, xs);
    // xs -> xs_t  (scan layout)
    transpose_kernel<<<dim3(DI / 32, M_ / 32), 256, 0, stream>>>(xs, xs_t);

    // 3) x_dbl = x_silu @ x_proj_w^T
    gemm_nt<128, 32, 0><<<dim3(160 / 32, M_ / 128), 256, 0, stream>>>(
        xs, DI, xpw, DI, xdbl, 160, DI, nullptr);

    // 4) dt (softplus) -> ybuf[bl][d], then transpose to dt_t
    gemm_nt<128, 128, 1><<<dim3(DI / 128, M_ / 128), 256, 0, stream>>>(
        xdbl, 160, dpw, DR, ybuf, DI, DR, dpb);
    transpose_kernel<<<dim3(DI / 32, M_ / 32), 256, 0, stream>>>(ybuf, dt_t);

    // B/C -> [n][bl]
    bc_transpose_kernel<<<(DS * M_) / 256, 256, 0, stream>>>(xdbl, Bt, Ct);

    // 5) chunked scan
    scan_phase1<<<B_ * 256 * NCH, 256, 0, stream>>>(dt_t, xs_t, Bt, alog, sfin, aprd);
    scan_phase2<<<NCHAIN / 256, 256, 0, stream>>>(sfin, aprd, pref);
    scan_phase3<<<B_ * 256 * NCH, 256, 0, stream>>>(dt_t, xs_t, Bt, Ct, alog, Dp, pref, ybuf);

    // 6) out = (y*z) @ out_proj_w^T  (split-bf16 MFMA; gating folded into split)
    split_gate_kernel<<<(M_ * DI / 4) / 256, 256, 0, stream>>>(ybuf, xz, yg_hi, yg_lo);
    split_bf16_kernel<<<(DM * DI / 4 + 255) / 256, 256, 0, stream>>>(opw, opw_hi, opw_lo, DM * DI / 4);
    gemm_mfma_split<128, 64><<<dim3(DM / 64, M_ / 128), 256, 0, stream>>>(
        yg_hi, yg_lo, opw_hi, opw_lo, out, M_, DM, DI);
}

// Round 4
// 967.283 us; speedup vs baseline: 2.8517x; 1.1738x over previous
//
#include <hip/hip_runtime.h>
#include <math.h>
#include <stdint.h>

#define B_ 2
#define L_ 1024
#define DM 2048
#define DI 4096
#define DS 16
#define DR 128
#define M_ (B_*L_)
#define NCH 16
#define LC  64
#define NCHAIN (B_*DI*DS)

typedef __attribute__((ext_vector_type(8))) __bf16 bf16x8;
typedef __attribute__((ext_vector_type(4))) float f32x4;

__device__ __forceinline__ float softplus_f(float x) {
    return (x > 20.0f) ? x : log1pf(expf(x));
}
__device__ __forceinline__ float silu_f(float x) {
    return x / (1.0f + expf(-x));
}
__device__ __forceinline__ short f2bf_rn(float x) {
    uint32_t u = __builtin_bit_cast(uint32_t, x);
    u += 0x7FFFu + ((u >> 16) & 1u);
    return (short)(u >> 16);
}
__device__ __forceinline__ float bf2f(short h) {
    uint32_t u = ((uint32_t)(unsigned short)h) << 16;
    return __builtin_bit_cast(float, u);
}
__device__ __forceinline__ void gload16(const void* g, void* l) {
    __builtin_amdgcn_global_load_lds(
        (const __attribute__((address_space(1))) void*)g,
        (__attribute__((address_space(3))) void*)l, 16, 0, 0);
}

// ---------------- bf16 split kernels ----------------
__global__ __launch_bounds__(256)
void split_bf16_kernel(const float* __restrict__ in, short* __restrict__ hi,
                       short* __restrict__ lo, int n4) {
    const int i = blockIdx.x * 256 + threadIdx.x;
    if (i >= n4) return;
    const float4 v = reinterpret_cast<const float4*>(in)[i];
    short4 h, l;
    h.x = f2bf_rn(v.x); l.x = f2bf_rn(v.x - bf2f(h.x));
    h.y = f2bf_rn(v.y); l.y = f2bf_rn(v.y - bf2f(h.y));
    h.z = f2bf_rn(v.z); l.z = f2bf_rn(v.z - bf2f(h.z));
    h.w = f2bf_rn(v.w); l.w = f2bf_rn(v.w - bf2f(h.w));
    reinterpret_cast<short4*>(hi)[i] = h;
    reinterpret_cast<short4*>(lo)[i] = l;
}

__global__ __launch_bounds__(256)
void split_gate_kernel(const float* __restrict__ y, const float* __restrict__ xz,
                       short* __restrict__ hi, short* __restrict__ lo) {
    const int i = blockIdx.x * 256 + threadIdx.x;
    const int d4 = i & (DI / 4 - 1);
    const int bl = i >> 10;
    const float4 yv = reinterpret_cast<const float4*>(y)[i];
    const float4 zv = *reinterpret_cast<const float4*>(
        &xz[(size_t)bl * 2 * DI + DI + d4 * 4]);
    float4 v;
    v.x = yv.x * zv.x; v.y = yv.y * zv.y; v.z = yv.z * zv.z; v.w = yv.w * zv.w;
    short4 h, l;
    h.x = f2bf_rn(v.x); l.x = f2bf_rn(v.x - bf2f(h.x));
    h.y = f2bf_rn(v.y); l.y = f2bf_rn(v.y - bf2f(h.y));
    h.z = f2bf_rn(v.z); l.z = f2bf_rn(v.z - bf2f(h.z));
    h.w = f2bf_rn(v.w); l.w = f2bf_rn(v.w - bf2f(h.w));
    reinterpret_cast<short4*>(hi)[i] = h;
    reinterpret_cast<short4*>(lo)[i] = l;
}

// ---------------- MFMA split-bf16 GEMM ----------------
// LDS chunk-transposed layout [kg][row][16B]: conflict-free ds_read_b128.
template<int BM, int BN, int LG2BM, int LG2BN>
__global__ __launch_bounds__(256)
void gemm_mfma_split(const short* __restrict__ Ahi, const short* __restrict__ Alo,
                     const short* __restrict__ Bhi, const short* __restrict__ Blo,
                     float* __restrict__ C, int M, int N, int K) {
    constexpr int BK = 32;
    constexpr int FM = BM / 32;
    constexpr int FN = BN / 32;
    __shared__ alignas(16) short sA[2][BM * BK];
    __shared__ alignas(16) short sB[2][BN * BK];

    const int tid  = threadIdx.x;
    const int wave = tid >> 6;
    const int lane = tid & 63;
    const int wm = wave >> 1, wn = wave & 1;
    const int m0 = blockIdx.y * BM;
    const int n0 = blockIdx.x * BN;
    const int frow = lane & 15;
    const int kg   = lane >> 4;

    f32x4 acc[FM][FN];
#pragma unroll
    for (int mi = 0; mi < FM; ++mi)
#pragma unroll
        for (int ni = 0; ni < FN; ++ni) acc[mi][ni] = (f32x4){0.f, 0.f, 0.f, 0.f};

    for (int kt = 0; kt < K; kt += BK) {
        // stage: chunk li -> LDS linear li*16B; source (row = li&(BM-1), kgc = li>>LG2BM)
#pragma unroll
        for (int r = 0; r < BM / 64; ++r) {
            const int li = r * 256 + tid;
            const int row = li & (BM - 1), kgc = li >> LG2BM;
            const size_t goff = (size_t)(m0 + row) * K + kt + kgc * 8;
            gload16(Ahi + goff, &sA[0][li << 3]);
            gload16(Alo + goff, &sA[1][li << 3]);
        }
#pragma unroll
        for (int r = 0; r < BN / 64; ++r) {
            const int li = r * 256 + tid;
            const int row = li & (BN - 1), kgc = li >> LG2BN;
            const size_t goff = (size_t)(n0 + row) * K + kt + kgc * 8;
            gload16(Bhi + goff, &sB[0][li << 3]);
            gload16(Blo + goff, &sB[1][li << 3]);
        }
        __syncthreads();

        bf16x8 ah[FM], al[FM], bh[FN], bl[FN];
#pragma unroll
        for (int mi = 0; mi < FM; ++mi) {
            const int idx = (kg * BM + wm * (BM / 2) + mi * 16 + frow) << 3;
            ah[mi] = *reinterpret_cast<const bf16x8*>(&sA[0][idx]);
            al[mi] = *reinterpret_cast<const bf16x8*>(&sA[1][idx]);
        }
#pragma unroll
        for (int ni = 0; ni < FN; ++ni) {
            const int idx = (kg * BN + wn * (BN / 2) + ni * 16 + frow) << 3;
            bh[ni] = *reinterpret_cast<const bf16x8*>(&sB[0][idx]);
            bl[ni] = *reinterpret_cast<const bf16x8*>(&sB[1][idx]);
        }
#pragma unroll
        for (int mi = 0; mi < FM; ++mi)
#pragma unroll
            for (int ni = 0; ni < FN; ++ni) {
                acc[mi][ni] = __builtin_amdgcn_mfma_f32_16x16x32_bf16(ah[mi], bh[ni], acc[mi][ni], 0, 0, 0);
                acc[mi][ni] = __builtin_amdgcn_mfma_f32_16x16x32_bf16(ah[mi], bl[ni], acc[mi][ni], 0, 0, 0);
                acc[mi][ni] = __builtin_amdgcn_mfma_f32_16x16x32_bf16(al[mi], bh[ni], acc[mi][ni], 0, 0, 0);
            }
        __syncthreads();
    }

    const int crow0 = m0 + wm * (BM / 2) + (lane >> 4) * 4;
    const int ccol0 = n0 + wn * (BN / 2) + (lane & 15);
#pragma unroll
    for (int mi = 0; mi < FM; ++mi)
#pragma unroll
        for (int ni = 0; ni < FN; ++ni)
#pragma unroll
            for (int r = 0; r < 4; ++r)
                C[(size_t)(crow0 + mi * 16 + r) * N + ccol0 + ni * 16] = acc[mi][ni][r];
}

// ---------------- fp32 vector GEMM ----------------
template<int BM, int BN, int MODE>
__global__ __launch_bounds__(256)
void gemm_nt(const float* __restrict__ A, int lda,
             const float* __restrict__ W, int ldw,
             float* __restrict__ C, int ldc,
             int K, const float* __restrict__ bias) {
    constexpr int BK = 16;
    constexpr int TM = BM / 16;
    constexpr int TN = BN / 16;
    __shared__ float As[BK][BM];
    __shared__ float Ws[BK][BN];
    const int tid = threadIdx.x;
    const int tx = tid & 15;
    const int ty = tid >> 4;
    const int m0 = blockIdx.y * BM;
    const int n0 = blockIdx.x * BN;

    float acc[TM][TN];
#pragma unroll
    for (int i = 0; i < TM; ++i)
#pragma unroll
        for (int j = 0; j < TN; ++j) acc[i][j] = 0.0f;

    for (int kt = 0; kt < K; kt += BK) {
        for (int v = tid; v < BM * 4; v += 256) {
            const int row = v >> 2;
            const int kq  = (v & 3) << 2;
            const float4 t = *reinterpret_cast<const float4*>(
                &A[(size_t)(m0 + row) * lda + kt + kq]);
            As[kq + 0][row] = t.x; As[kq + 1][row] = t.y;
            As[kq + 2][row] = t.z; As[kq + 3][row] = t.w;
        }
        for (int v = tid; v < BN * 4; v += 256) {
            const int row = v >> 2;
            const int kq  = (v & 3) << 2;
            const float4 t = *reinterpret_cast<const float4*>(
                &W[(size_t)(n0 + row) * ldw + kt + kq]);
            Ws[kq + 0][row] = t.x; Ws[kq + 1][row] = t.y;
            Ws[kq + 2][row] = t.z; Ws[kq + 3][row] = t.w;
        }
        __syncthreads();
#pragma unroll
        for (int kk = 0; kk < BK; ++kk) {
            float a[TM], w[TN];
#pragma unroll
            for (int i = 0; i < TM; ++i) a[i] = As[kk][ty * TM + i];
#pragma unroll
            for (int j = 0; j < TN; ++j) w[j] = Ws[kk][tx * TN + j];
#pragma unroll
            for (int i = 0; i < TM; ++i)
#pragma unroll
                for (int j = 0; j < TN; ++j)
                    acc[i][j] = fmaf(a[i], w[j], acc[i][j]);
        }
        __syncthreads();
    }

#pragma unroll
    for (int i = 0; i < TM; ++i) {
        const size_t rowoff = (size_t)(m0 + ty * TM + i) * ldc + n0 + tx * TN;
#pragma unroll
        for (int j = 0; j < TN; ++j) {
            float v = acc[i][j];
            if constexpr (MODE == 1) {
                v = softplus_f(v + 2.0f * bias[n0 + tx * TN + j]);
            }
            C[rowoff + j] = v;
        }
    }
}

// ---------------- split-K fp32 GEMM (skinny x_proj) ----------------
// partial[z][M][ldc] over K slice [z*KSL, (z+1)*KSL)
template<int BM, int BN, int KSL>
__global__ __launch_bounds__(256)
void gemm_nt_splitk(const float* __restrict__ A, int lda,
                    const float* __restrict__ W, int ldw,
                    float* __restrict__ pbuf, int ldc, int M) {
    constexpr int BK = 16;
    constexpr int TM = BM / 16;
    constexpr int TN = BN / 16;
    __shared__ float As[BK][BM];
    __shared__ float Ws[BK][BN];
    const int tid = threadIdx.x;
    const int tx = tid & 15;
    const int ty = tid >> 4;
    const int m0 = blockIdx.y * BM;
    const int n0 = blockIdx.x * BN;
    const int k0 = blockIdx.z * KSL;

    float acc[TM][TN];
#pragma unroll
    for (int i = 0; i < TM; ++i)
#pragma unroll
        for (int j = 0; j < TN; ++j) acc[i][j] = 0.0f;

    for (int kt = k0; kt < k0 + KSL; kt += BK) {
        for (int v = tid; v < BM * 4; v += 256) {
            const int row = v >> 2;
            const int kq  = (v & 3) << 2;
            const float4 t = *reinterpret_cast<const float4*>(
                &A[(size_t)(m0 + row) * lda + kt + kq]);
            As[kq + 0][row] = t.x; As[kq + 1][row] = t.y;
            As[kq + 2][row] = t.z; As[kq + 3][row] = t.w;
        }
        for (int v = tid; v < BN * 4; v += 256) {
            const int row = v >> 2;
            const int kq  = (v & 3) << 2;
            const float4 t = *reinterpret_cast<const float4*>(
                &W[(size_t)(n0 + row) * ldw + kt + kq]);
            Ws[kq + 0][row] = t.x; Ws[kq + 1][row] = t.y;
            Ws[kq + 2][row] = t.z; Ws[kq + 3][row] = t.w;
        }
        __syncthreads();
#pragma unroll
        for (int kk = 0; kk < BK; ++kk) {
            float a[TM], w[TN];
#pragma unroll
            for (int i = 0; i < TM; ++i) a[i] = As[kk][ty * TM + i];
#pragma unroll
            for (int j = 0; j < TN; ++j) w[j] = Ws[kk][tx * TN + j];
#pragma unroll
            for (int i = 0; i < TM; ++i)
#pragma unroll
                for (int j = 0; j < TN; ++j)
                    acc[i][j] = fmaf(a[i], w[j], acc[i][j]);
        }
        __syncthreads();
    }

    float* outp = pbuf + (size_t)blockIdx.z * M * ldc;
#pragma unroll
    for (int i = 0; i < TM; ++i) {
        const size_t rowoff = (size_t)(m0 + ty * TM + i) * ldc + n0 + tx * TN;
#pragma unroll
        for (int j = 0; j < TN; ++j) outp[rowoff + j] = acc[i][j];
    }
}

__global__ __launch_bounds__(256)
void reduce_splitk(const float* __restrict__ pbuf, float* __restrict__ outp,
                   int n, int parts) {
    const int i = blockIdx.x * 256 + threadIdx.x;
    if (i >= n) return;
    float s = 0.f;
    for (int z = 0; z < parts; ++z) s += pbuf[(size_t)z * n + i];
    outp[i] = s;
}

// ---------------- conv + bias + silu ----------------
__global__ __launch_bounds__(256)
void conv_silu_kernel(const float* __restrict__ xz, const float* __restrict__ cw,
                      const float* __restrict__ cb, float* __restrict__ xs) {
    const int idx = blockIdx.x * 256 + threadIdx.x;
    const int d  = idx & (DI - 1);
    const int bl = idx >> 12;
    const int l  = bl & (L_ - 1);
    const int b0 = bl - l;
    float s = cb[d];
    const float w0 = cw[d * 4 + 0], w1 = cw[d * 4 + 1];
    const float w2 = cw[d * 4 + 2], w3 = cw[d * 4 + 3];
    if (l >= 3) {
        const float* p = xz + (size_t)bl * (2 * DI) + d;
        s += p[-(size_t)3 * 2 * DI] * w0 + p[-(size_t)2 * 2 * DI] * w1
           + p[-(size_t)1 * 2 * DI] * w2 + p[0] * w3;
    } else {
        const float wk[4] = {w0, w1, w2, w3};
#pragma unroll
        for (int k = 0; k < 4; ++k) {
            const int ls = l - 3 + k;
            if (ls >= 0) s += xz[(size_t)(b0 + ls) * (2 * DI) + d] * wk[k];
        }
    }
    xs[idx] = silu_f(s);
}

// ---------------- tiled transpose [M_][DI] -> [DI][M_] ----------------
__global__ __launch_bounds__(256)
void transpose_kernel(const float* __restrict__ src, float* __restrict__ dst) {
    __shared__ float tile[32][33];
    const int bx = blockIdx.x;
    const int by = blockIdx.y;
    const int tx = threadIdx.x & 31;
    const int ty = threadIdx.x >> 5;
#pragma unroll
    for (int r = 0; r < 32; r += 8)
        tile[ty + r][tx] = src[(size_t)(by * 32 + ty + r) * DI + bx * 32 + tx];
    __syncthreads();
#pragma unroll
    for (int r = 0; r < 32; r += 8)
        dst[(size_t)(bx * 32 + ty + r) * M_ + by * 32 + tx] = tile[tx][ty + r];
}

// ---------------- B/C transpose ----------------
__global__ __launch_bounds__(256)
void bc_transpose_kernel(const float* __restrict__ xdbl,
                         float* __restrict__ Bt, float* __restrict__ Ct) {
    const int idx = blockIdx.x * 256 + threadIdx.x;
    const int bl = idx & (M_ - 1);
    const int n  = idx >> 11;
    Bt[idx] = xdbl[(size_t)bl * 160 + 128 + n];
    Ct[idx] = xdbl[(size_t)bl * 160 + 144 + n];
}

// ---------------- scan phase 1 ----------------
__global__ __launch_bounds__(256)
void scan_phase1(const float* __restrict__ dt_t, const float* __restrict__ xs_t,
                 const float* __restrict__ Bt, const float* __restrict__ alog,
                 float* __restrict__ sfin, float* __restrict__ aprod) {
    const int c    = blockIdx.x & 15;
    const int dblk = (blockIdx.x >> 4) & 255;
    const int b    = blockIdx.x >> 12;
    const int tid  = threadIdx.x;
    const int n  = tid & 15;
    const int dg = tid >> 4;
    const int d  = dblk * 16 + dg;

    const float Av = -expf(alog[d * DS + n]);
    const size_t rowoff = (size_t)d * M_ + b * L_ + c * LC;
    const float* dtp = dt_t + rowoff;
    const float* xsp = xs_t + rowoff;
    const float* Bp  = Bt + (size_t)n * M_ + b * L_ + c * LC;

    float s = 0.f, dts = 0.f;
#pragma unroll 4
    for (int l = 0; l < LC; l += 4) {
        const float4 dt4 = *reinterpret_cast<const float4*>(dtp + l);
        const float4 x4  = *reinterpret_cast<const float4*>(xsp + l);
        const float4 b4  = *reinterpret_cast<const float4*>(Bp + l);
        s = fmaf(__expf(dt4.x * Av), s, dt4.x * b4.x * x4.x); dts += dt4.x;
        s = fmaf(__expf(dt4.y * Av), s, dt4.y * b4.y * x4.y); dts += dt4.y;
        s = fmaf(__expf(dt4.z * Av), s, dt4.z * b4.z * x4.z); dts += dt4.z;
        s = fmaf(__expf(dt4.w * Av), s, dt4.w * b4.w * x4.w); dts += dt4.w;
    }
    const size_t o = (size_t)c * NCHAIN + ((size_t)(b * DI + d)) * DS + n;
    sfin[o]  = s;
    aprod[o] = __expf(Av * dts);
}

// ---------------- scan phase 2 ----------------
__global__ __launch_bounds__(256)
void scan_phase2(const float* __restrict__ sfin, const float* __restrict__ aprod,
                 float* __restrict__ prefix) {
    const int t = blockIdx.x * 256 + threadIdx.x;
    float p = 0.f;
#pragma unroll
    for (int c = 0; c < NCH; ++c) {
        const size_t o = (size_t)c * NCHAIN + t;
        prefix[o] = p;
        p = fmaf(aprod[o], p, sfin[o]);
    }
}

// ---------------- scan phase 3 ----------------
__global__ __launch_bounds__(256)
void scan_phase3(const float* __restrict__ dt_t, const float* __restrict__ xs_t,
                 const float* __restrict__ Bt, const float* __restrict__ Ct,
                 const float* __restrict__ alog, const float* __restrict__ Dp,
                 const float* __restrict__ prefix, float* __restrict__ ybuf) {
    const int c    = blockIdx.x & 15;
    const int dblk = (blockIdx.x >> 4) & 255;
    const int b    = blockIdx.x >> 12;
    const int tid  = threadIdx.x;
    const int n  = tid & 15;
    const int dg = tid >> 4;
    const int d  = dblk * 16 + dg;

    const float Av = -expf(alog[d * DS + n]);
    const float Dv = Dp[d];
    float s = prefix[(size_t)c * NCHAIN + ((size_t)(b * DI + d)) * DS + n];

    const size_t rowoff = (size_t)d * M_ + b * L_ + c * LC;
    const float* dtp = dt_t + rowoff;
    const float* xsp = xs_t + rowoff;
    const float* Bp  = Bt + (size_t)n * M_ + b * L_ + c * LC;
    const float* Cp  = Ct + (size_t)n * M_ + b * L_ + c * LC;
    float* yout = ybuf + (size_t)(b * L_ + c * LC) * DI + d;

#pragma unroll 2
    for (int l = 0; l < LC; l += 4) {
        const float4 dt4 = *reinterpret_cast<const float4*>(dtp + l);
        const float4 x4  = *reinterpret_cast<const float4*>(xsp + l);
        const float4 b4  = *reinterpret_cast<const float4*>(Bp + l);
        const float4 c4  = *reinterpret_cast<const float4*>(Cp + l);
#pragma unroll
        for (int k = 0; k < 4; ++k) {
            const float dt = (k == 0) ? dt4.x : (k == 1) ? dt4.y : (k == 2) ? dt4.z : dt4.w;
            const float x  = (k == 0) ? x4.x  : (k == 1) ? x4.y  : (k == 2) ? x4.z  : x4.w;
            const float Bv = (k == 0) ? b4.x  : (k == 1) ? b4.y  : (k == 2) ? b4.z  : b4.w;
            const float Cv = (k == 0) ? c4.x  : (k == 1) ? c4.y  : (k == 2) ? c4.z  : c4.w;
            s = fmaf(__expf(dt * Av), s, dt * Bv * x);
            float contrib = s * Cv;
            contrib += __shfl_xor(contrib, 1);
            contrib += __shfl_xor(contrib, 2);
            contrib += __shfl_xor(contrib, 4);
            contrib += __shfl_xor(contrib, 8);
            if (n == 0) yout[(size_t)(l + k) * DI] = fmaf(x, Dv, contrib);
        }
    }
}

extern "C" void kernel_launch(void* const* d_in, const int* in_sizes, int n_in,
                              void* d_out, int out_size, void* d_ws, size_t ws_size,
                              hipStream_t stream) {
    const float* hs   = (const float*)d_in[0];
    const float* ipw  = (const float*)d_in[1];
    const float* cw   = (const float*)d_in[2];
    const float* cb   = (const float*)d_in[3];
    const float* xpw  = (const float*)d_in[4];
    const float* dpw  = (const float*)d_in[5];
    const float* dpb  = (const float*)d_in[6];
    const float* alog = (const float*)d_in[7];
    const float* Dp   = (const float*)d_in[8];
    const float* opw  = (const float*)d_in[9];
    float* out = (float*)d_out;

    float* ws    = (float*)d_ws;
    float* xz    = ws;                              // 16,777,216 f
    float* xs    = xz   + (size_t)16777216;         //  8,388,608 f
    float* xdbl  = xs   + (size_t)8388608;          //    327,680 f
    float* ybuf  = xdbl + (size_t)327680;           //  8,388,608 f (dt, then y)
    float* Bt    = ybuf + (size_t)8388608;          //     32,768 f
    float* Ct    = Bt   + (size_t)32768;            //     32,768 f
    float* R     = Ct   + (size_t)32768;

    // R region, scan view
    float* xs_t  = R;                               // 8,388,608 f
    float* dt_t  = R + (size_t)8388608;             // 8,388,608 f
    float* sfin  = R + (size_t)16777216;            // 2,097,152 f
    float* aprd  = sfin + (size_t)2097152;
    float* pref  = aprd + (size_t)2097152;
    // split-K partials for GEMM3: occupy the (not-yet-written) dt_t region
    float* pbuf  = dt_t;                            // 16*2048*160 = 5,242,880 f
    // R region, phase-1 split view (dead after GEMM1)
    short* hs_hi  = (short*)R;
    short* hs_lo  = hs_hi + (size_t)M_ * DM;
    short* ipw_hi = hs_lo + (size_t)M_ * DM;
    short* ipw_lo = ipw_hi + (size_t)2 * DI * DM;
    // R region, phase-2 split view (written after scan dies)
    short* yg_hi  = (short*)R;
    short* yg_lo  = yg_hi + (size_t)M_ * DI;
    short* opw_hi = yg_lo + (size_t)M_ * DI;
    short* opw_lo = opw_hi + (size_t)DM * DI;

    // 1) xz = hs @ in_proj_w^T  (split-bf16 MFMA)
    split_bf16_kernel<<<(M_ * DM / 4 + 255) / 256, 256, 0, stream>>>(hs, hs_hi, hs_lo, M_ * DM / 4);
    split_bf16_kernel<<<(2 * DI * DM / 4 + 255) / 256, 256, 0, stream>>>(ipw, ipw_hi, ipw_lo, 2 * DI * DM / 4);
    gemm_mfma_split<128, 128, 7, 7><<<dim3(2 * DI / 128, M_ / 128), 256, 0, stream>>>(
        hs_hi, hs_lo, ipw_hi, ipw_lo, xz, M_, 2 * DI, DM);

    // 2) conv + silu; transpose for scan
    conv_silu_kernel<<<(B_ * L_ * DI) / 256, 256, 0, stream>>>(xz, cw, cb, xs);
    transpose_kernel<<<dim3(DI / 32, M_ / 32), 256, 0, stream>>>(xs, xs_t);

    // 3) x_dbl = x_silu @ x_proj_w^T  (split-K: 5 x 16 x 16 blocks)
    gemm_nt_splitk<128, 32, 256><<<dim3(160 / 32, M_ / 128, 16), 256, 0, stream>>>(
        xs, DI, xpw, DI, pbuf, 160, M_);
    reduce_splitk<<<(M_ * 160 + 255) / 256, 256, 0, stream>>>(pbuf, xdbl, M_ * 160, 16);

    // 4) dt (softplus) -> ybuf, then transpose to dt_t
    gemm_nt<128, 128, 1><<<dim3(DI / 128, M_ / 128), 256, 0, stream>>>(
        xdbl, 160, dpw, DR, ybuf, DI, DR, dpb);
    transpose_kernel<<<dim3(DI / 32, M_ / 32), 256, 0, stream>>>(ybuf, dt_t);

    bc_transpose_kernel<<<(DS * M_) / 256, 256, 0, stream>>>(xdbl, Bt, Ct);

    // 5) chunked scan
    scan_phase1<<<B_ * 256 * NCH, 256, 0, stream>>>(dt_t, xs_t, Bt, alog, sfin, aprd);
    scan_phase2<<<NCHAIN / 256, 256, 0, stream>>>(sfin, aprd, pref);
    scan_phase3<<<B_ * 256 * NCH, 256, 0, stream>>>(dt_t, xs_t, Bt, Ct, alog, Dp, pref, ybuf);

    // 6) out = (y*z) @ out_proj_w^T  (split-bf16 MFMA)
    split_gate_kernel<<<(M_ * DI / 4) / 256, 256, 0, stream>>>(ybuf, xz, yg_hi, yg_lo);
    split_bf16_kernel<<<(DM * DI / 4 + 255) / 256, 256, 0, stream>>>(opw, opw_hi, opw_lo, DM * DI / 4);
    gemm_mfma_split<128, 64, 7, 6><<<dim3(DM / 64, M_ / 128), 256, 0, stream>>>(
        yg_hi, yg_lo, opw_hi, opw_lo, out, M_, DM, DI);
}

// Round 5
// 918.956 us; speedup vs baseline: 3.0016x; 1.0526x over previous
//
#include <hip/hip_runtime.h>
#include <math.h>
#include <stdint.h>

#define B_ 2
#define L_ 1024
#define DM 2048
#define DI 4096
#define DS 16
#define DR 128
#define M_ (B_*L_)
#define NCH 16
#define LC  64
#define NCHAIN (B_*DI*DS)

typedef __attribute__((ext_vector_type(8))) __bf16 bf16x8;
typedef __attribute__((ext_vector_type(4))) float f32x4;

__device__ __forceinline__ float softplus_f(float x) {
    return (x > 20.0f) ? x : log1pf(expf(x));
}
__device__ __forceinline__ float silu_f(float x) {
    return x / (1.0f + expf(-x));
}
__device__ __forceinline__ short f2bf_rn(float x) {
    uint32_t u = __builtin_bit_cast(uint32_t, x);
    u += 0x7FFFu + ((u >> 16) & 1u);
    return (short)(u >> 16);
}
__device__ __forceinline__ float bf2f(short h) {
    uint32_t u = ((uint32_t)(unsigned short)h) << 16;
    return __builtin_bit_cast(float, u);
}
__device__ __forceinline__ void gload16(const void* g, void* l) {
    __builtin_amdgcn_global_load_lds(
        (const __attribute__((address_space(1))) void*)g,
        (__attribute__((address_space(3))) void*)l, 16, 0, 0);
}

// ---------------- bf16 split kernels ----------------
__global__ __launch_bounds__(256)
void split_bf16_kernel(const float* __restrict__ in, short* __restrict__ hi,
                       short* __restrict__ lo, int n4) {
    const int i = blockIdx.x * 256 + threadIdx.x;
    if (i >= n4) return;
    const float4 v = reinterpret_cast<const float4*>(in)[i];
    short4 h, l;
    h.x = f2bf_rn(v.x); l.x = f2bf_rn(v.x - bf2f(h.x));
    h.y = f2bf_rn(v.y); l.y = f2bf_rn(v.y - bf2f(h.y));
    h.z = f2bf_rn(v.z); l.z = f2bf_rn(v.z - bf2f(h.z));
    h.w = f2bf_rn(v.w); l.w = f2bf_rn(v.w - bf2f(h.w));
    reinterpret_cast<short4*>(hi)[i] = h;
    reinterpret_cast<short4*>(lo)[i] = l;
}

__global__ __launch_bounds__(256)
void split_gate_kernel(const float* __restrict__ y, const float* __restrict__ xz,
                       short* __restrict__ hi, short* __restrict__ lo) {
    const int i = blockIdx.x * 256 + threadIdx.x;
    const int d4 = i & (DI / 4 - 1);
    const int bl = i >> 10;
    const float4 yv = reinterpret_cast<const float4*>(y)[i];
    const float4 zv = *reinterpret_cast<const float4*>(
        &xz[(size_t)bl * 2 * DI + DI + d4 * 4]);
    float4 v;
    v.x = yv.x * zv.x; v.y = yv.y * zv.y; v.z = yv.z * zv.z; v.w = yv.w * zv.w;
    short4 h, l;
    h.x = f2bf_rn(v.x); l.x = f2bf_rn(v.x - bf2f(h.x));
    h.y = f2bf_rn(v.y); l.y = f2bf_rn(v.y - bf2f(h.y));
    h.z = f2bf_rn(v.z); l.z = f2bf_rn(v.z - bf2f(h.z));
    h.w = f2bf_rn(v.w); l.w = f2bf_rn(v.w - bf2f(h.w));
    reinterpret_cast<short4*>(hi)[i] = h;
    reinterpret_cast<short4*>(lo)[i] = l;
}

// ---------------- MFMA split-bf16 GEMM, double-buffered + counted vmcnt ----
// LDS chunk-transposed layout [kgc][row][16B]: conflict-free ds_read_b128.
// Pipeline: stage(next) -> vmcnt(NLD) [prev tile done, next in flight]
//           -> s_barrier -> ds_read+MFMA -> s_barrier.
template<int BM, int BN, int LG2BM, int LG2BN>
__global__ __launch_bounds__(256)
void gemm_mfma_split(const short* __restrict__ Ahi, const short* __restrict__ Alo,
                     const short* __restrict__ Bhi, const short* __restrict__ Blo,
                     float* __restrict__ C, int M, int N, int K) {
    constexpr int BK = 32;
    constexpr int FM = BM / 32;
    constexpr int FN = BN / 32;
    constexpr int NLD = (BM / 64) * 2 + (BN / 64) * 2;  // gload_lds per thread per stage
    __shared__ alignas(16) short sA[2][2][BM * BK];
    __shared__ alignas(16) short sB[2][2][BN * BK];

    const int tid  = threadIdx.x;
    const int wave = tid >> 6;
    const int lane = tid & 63;
    const int wm = wave >> 1, wn = wave & 1;
    const int m0 = blockIdx.y * BM;
    const int n0 = blockIdx.x * BN;
    const int frow = lane & 15;
    const int kg   = lane >> 4;

    // precomputed per-thread global base offsets (add kt per stage)
    size_t baseA[BM / 64], baseB[BN / 64];
#pragma unroll
    for (int r = 0; r < BM / 64; ++r) {
        const int li = r * 256 + tid;
        baseA[r] = (size_t)(m0 + (li & (BM - 1))) * K + (li >> LG2BM) * 8;
    }
#pragma unroll
    for (int r = 0; r < BN / 64; ++r) {
        const int li = r * 256 + tid;
        baseB[r] = (size_t)(n0 + (li & (BN - 1))) * K + (li >> LG2BN) * 8;
    }

    auto stage = [&](int buf, int kt) {
#pragma unroll
        for (int r = 0; r < BM / 64; ++r) {
            const int li = r * 256 + tid;
            gload16(Ahi + baseA[r] + kt, &sA[buf][0][li << 3]);
            gload16(Alo + baseA[r] + kt, &sA[buf][1][li << 3]);
        }
#pragma unroll
        for (int r = 0; r < BN / 64; ++r) {
            const int li = r * 256 + tid;
            gload16(Bhi + baseB[r] + kt, &sB[buf][0][li << 3]);
            gload16(Blo + baseB[r] + kt, &sB[buf][1][li << 3]);
        }
    };

    f32x4 acc[FM][FN];
#pragma unroll
    for (int mi = 0; mi < FM; ++mi)
#pragma unroll
        for (int ni = 0; ni < FN; ++ni) acc[mi][ni] = (f32x4){0.f, 0.f, 0.f, 0.f};

    stage(0, 0);
    const int NT = K / BK;
    int cur = 0;
    for (int t = 0; t < NT; ++t) {
        if (t + 1 < NT) {
            stage(cur ^ 1, (t + 1) * BK);
            // wait only for the CURRENT tile's NLD loads; next tile stays in flight
            if constexpr (NLD == 8)      asm volatile("s_waitcnt vmcnt(8)" ::: "memory");
            else if constexpr (NLD == 6) asm volatile("s_waitcnt vmcnt(6)" ::: "memory");
            else                         asm volatile("s_waitcnt vmcnt(0)" ::: "memory");
        } else {
            asm volatile("s_waitcnt vmcnt(0)" ::: "memory");
        }
        __builtin_amdgcn_s_barrier();   // all waves' current-tile loads complete

        bf16x8 ah[FM], al[FM], bh[FN], bl[FN];
#pragma unroll
        for (int mi = 0; mi < FM; ++mi) {
            const int idx = (kg * BM + wm * (BM / 2) + mi * 16 + frow) << 3;
            ah[mi] = *reinterpret_cast<const bf16x8*>(&sA[cur][0][idx]);
            al[mi] = *reinterpret_cast<const bf16x8*>(&sA[cur][1][idx]);
        }
#pragma unroll
        for (int ni = 0; ni < FN; ++ni) {
            const int idx = (kg * BN + wn * (BN / 2) + ni * 16 + frow) << 3;
            bh[ni] = *reinterpret_cast<const bf16x8*>(&sB[cur][0][idx]);
            bl[ni] = *reinterpret_cast<const bf16x8*>(&sB[cur][1][idx]);
        }
        __builtin_amdgcn_s_setprio(1);
#pragma unroll
        for (int mi = 0; mi < FM; ++mi)
#pragma unroll
            for (int ni = 0; ni < FN; ++ni) {
                acc[mi][ni] = __builtin_amdgcn_mfma_f32_16x16x32_bf16(ah[mi], bh[ni], acc[mi][ni], 0, 0, 0);
                acc[mi][ni] = __builtin_amdgcn_mfma_f32_16x16x32_bf16(ah[mi], bl[ni], acc[mi][ni], 0, 0, 0);
                acc[mi][ni] = __builtin_amdgcn_mfma_f32_16x16x32_bf16(al[mi], bh[ni], acc[mi][ni], 0, 0, 0);
            }
        __builtin_amdgcn_s_setprio(0);
        __builtin_amdgcn_s_barrier();   // reads of buf[cur] done -> next stage may overwrite
        cur ^= 1;
    }

    const int crow0 = m0 + wm * (BM / 2) + (lane >> 4) * 4;
    const int ccol0 = n0 + wn * (BN / 2) + (lane & 15);
#pragma unroll
    for (int mi = 0; mi < FM; ++mi)
#pragma unroll
        for (int ni = 0; ni < FN; ++ni)
#pragma unroll
            for (int r = 0; r < 4; ++r)
                C[(size_t)(crow0 + mi * 16 + r) * N + ccol0 + ni * 16] = acc[mi][ni][r];
}

// ---------------- fp32 vector GEMM ----------------
// MODE 0: plain. MODE 2: C = softplus(acc + 2*bias[m])  (bias per ROW)
template<int BM, int BN, int MODE>
__global__ __launch_bounds__(256)
void gemm_nt(const float* __restrict__ A, int lda,
             const float* __restrict__ W, int ldw,
             float* __restrict__ C, int ldc,
             int K, const float* __restrict__ bias) {
    constexpr int BK = 16;
    constexpr int TM = BM / 16;
    constexpr int TN = BN / 16;
    __shared__ float As[BK][BM];
    __shared__ float Ws[BK][BN];
    const int tid = threadIdx.x;
    const int tx = tid & 15;
    const int ty = tid >> 4;
    const int m0 = blockIdx.y * BM;
    const int n0 = blockIdx.x * BN;

    float acc[TM][TN];
#pragma unroll
    for (int i = 0; i < TM; ++i)
#pragma unroll
        for (int j = 0; j < TN; ++j) acc[i][j] = 0.0f;

    for (int kt = 0; kt < K; kt += BK) {
        for (int v = tid; v < BM * 4; v += 256) {
            const int row = v >> 2;
            const int kq  = (v & 3) << 2;
            const float4 t = *reinterpret_cast<const float4*>(
                &A[(size_t)(m0 + row) * lda + kt + kq]);
            As[kq + 0][row] = t.x; As[kq + 1][row] = t.y;
            As[kq + 2][row] = t.z; As[kq + 3][row] = t.w;
        }
        for (int v = tid; v < BN * 4; v += 256) {
            const int row = v >> 2;
            const int kq  = (v & 3) << 2;
            const float4 t = *reinterpret_cast<const float4*>(
                &W[(size_t)(n0 + row) * ldw + kt + kq]);
            Ws[kq + 0][row] = t.x; Ws[kq + 1][row] = t.y;
            Ws[kq + 2][row] = t.z; Ws[kq + 3][row] = t.w;
        }
        __syncthreads();
#pragma unroll
        for (int kk = 0; kk < BK; ++kk) {
            float a[TM], w[TN];
#pragma unroll
            for (int i = 0; i < TM; ++i) a[i] = As[kk][ty * TM + i];
#pragma unroll
            for (int j = 0; j < TN; ++j) w[j] = Ws[kk][tx * TN + j];
#pragma unroll
            for (int i = 0; i < TM; ++i)
#pragma unroll
                for (int j = 0; j < TN; ++j)
                    acc[i][j] = fmaf(a[i], w[j], acc[i][j]);
        }
        __syncthreads();
    }

#pragma unroll
    for (int i = 0; i < TM; ++i) {
        const size_t rowoff = (size_t)(m0 + ty * TM + i) * ldc + n0 + tx * TN;
        float bm = 0.f;
        if constexpr (MODE == 2) bm = 2.0f * bias[m0 + ty * TM + i];
#pragma unroll
        for (int j = 0; j < TN; ++j) {
            float v = acc[i][j];
            if constexpr (MODE == 2) v = softplus_f(v + bm);
            C[rowoff + j] = v;
        }
    }
}

// ---------------- split-K fp32 GEMM, A read from transposed xs_t ----------
// A'[m][k] = At[k][m]; C partial[z][M][ldc] over K slice [z*KSL,(z+1)*KSL)
template<int BM, int BN, int KSL>
__global__ __launch_bounds__(256)
void gemm_splitk_T(const float* __restrict__ At,
                   const float* __restrict__ W, int ldw,
                   float* __restrict__ pbuf, int ldc, int M) {
    constexpr int BK = 16;
    constexpr int TM = BM / 16;
    constexpr int TN = BN / 16;
    __shared__ float As[BK][BM];
    __shared__ float Ws[BK][BN];
    const int tid = threadIdx.x;
    const int tx = tid & 15;
    const int ty = tid >> 4;
    const int m0 = blockIdx.y * BM;
    const int n0 = blockIdx.x * BN;
    const int k0 = blockIdx.z * KSL;

    float acc[TM][TN];
#pragma unroll
    for (int i = 0; i < TM; ++i)
#pragma unroll
        for (int j = 0; j < TN; ++j) acc[i][j] = 0.0f;

    for (int kt = k0; kt < k0 + KSL; kt += BK) {
        // A tile: 16 k-rows, each contiguous in m -> direct coalesced copy
        for (int v = tid; v < BK * BM / 4; v += 256) {
            const int kk = v >> 5;            // BM/4 = 32 float4 per row
            const int m4 = (v & 31) << 2;
            *reinterpret_cast<float4*>(&As[kk][m4]) =
                *reinterpret_cast<const float4*>(&At[(size_t)(kt + kk) * M + m0 + m4]);
        }
        for (int v = tid; v < BN * 4; v += 256) {
            const int row = v >> 2;
            const int kq  = (v & 3) << 2;
            const float4 t = *reinterpret_cast<const float4*>(
                &W[(size_t)(n0 + row) * ldw + kt + kq]);
            Ws[kq + 0][row] = t.x; Ws[kq + 1][row] = t.y;
            Ws[kq + 2][row] = t.z; Ws[kq + 3][row] = t.w;
        }
        __syncthreads();
#pragma unroll
        for (int kk = 0; kk < BK; ++kk) {
            float a[TM], w[TN];
#pragma unroll
            for (int i = 0; i < TM; ++i) a[i] = As[kk][ty * TM + i];
#pragma unroll
            for (int j = 0; j < TN; ++j) w[j] = Ws[kk][tx * TN + j];
#pragma unroll
            for (int i = 0; i < TM; ++i)
#pragma unroll
                for (int j = 0; j < TN; ++j)
                    acc[i][j] = fmaf(a[i], w[j], acc[i][j]);
        }
        __syncthreads();
    }

    float* outp = pbuf + (size_t)blockIdx.z * M * ldc;
#pragma unroll
    for (int i = 0; i < TM; ++i) {
        const size_t rowoff = (size_t)(m0 + ty * TM + i) * ldc + n0 + tx * TN;
#pragma unroll
        for (int j = 0; j < TN; ++j) outp[rowoff + j] = acc[i][j];
    }
}

// reduce split-K partials; route dt-rank cols to xdbl, B/C cols to Bt/Ct
__global__ __launch_bounds__(256)
void reduce_bc(const float* __restrict__ pbuf, float* __restrict__ xdbl,
               float* __restrict__ Bt, float* __restrict__ Ct) {
    const int i = blockIdx.x * 256 + threadIdx.x;
    if (i >= M_ * 160) return;
    float s = 0.f;
#pragma unroll
    for (int z = 0; z < 16; ++z) s += pbuf[(size_t)z * M_ * 160 + i];
    const int bl = i / 160;
    const int c  = i - bl * 160;
    if (c < 128)      xdbl[i] = s;
    else if (c < 144) Bt[(size_t)(c - 128) * M_ + bl] = s;
    else              Ct[(size_t)(c - 144) * M_ + bl] = s;
}

// ---------------- conv + bias + silu, transposed output ----------------
// xs_t[d][b*L+l] = silu(conv(x)[b,l,d]); tile 64d x 32l per block
__global__ __launch_bounds__(256)
void conv_silu_t(const float* __restrict__ xz, const float* __restrict__ cw,
                 const float* __restrict__ cb, float* __restrict__ xs_t) {
    __shared__ float tin[35][64];
    __shared__ float tout[64][33];
    const int d0 = blockIdx.x * 64;
    const int l0 = blockIdx.y * 32;
    const int b  = blockIdx.z;
    const int tid = threadIdx.x;

    for (int v = tid; v < 35 * 16; v += 256) {
        const int row = v >> 4;
        const int c4  = (v & 15) << 2;
        const int l = l0 - 3 + row;
        float4 t = {0.f, 0.f, 0.f, 0.f};
        if (l >= 0)
            t = *reinterpret_cast<const float4*>(
                &xz[(size_t)(b * L_ + l) * 2 * DI + d0 + c4]);
        *reinterpret_cast<float4*>(&tin[row][c4]) = t;
    }
    __syncthreads();

    const int dl = tid & 63;
    const int lq = tid >> 6;
    const float w0 = cw[(d0 + dl) * 4 + 0], w1 = cw[(d0 + dl) * 4 + 1];
    const float w2 = cw[(d0 + dl) * 4 + 2], w3 = cw[(d0 + dl) * 4 + 3];
    const float bias = cb[d0 + dl];
#pragma unroll
    for (int li = lq; li < 32; li += 4) {
        const float s = bias + tin[li][dl] * w0 + tin[li + 1][dl] * w1
                      + tin[li + 2][dl] * w2 + tin[li + 3][dl] * w3;
        tout[dl][li] = silu_f(s);
    }
    __syncthreads();

    for (int v = tid; v < 64 * 8; v += 256) {
        const int row = v >> 3;
        const int c4  = (v & 7) << 2;
        float4 t;
        t.x = tout[row][c4 + 0]; t.y = tout[row][c4 + 1];
        t.z = tout[row][c4 + 2]; t.w = tout[row][c4 + 3];
        *reinterpret_cast<float4*>(&xs_t[(size_t)(d0 + row) * M_ + b * L_ + l0 + c4]) = t;
    }
}

// ---------------- scan phase 1 ----------------
__global__ __launch_bounds__(256)
void scan_phase1(const float* __restrict__ dt_t, const float* __restrict__ xs_t,
                 const float* __restrict__ Bt, const float* __restrict__ alog,
                 float* __restrict__ sfin, float* __restrict__ aprod) {
    const int c    = blockIdx.x & 15;
    const int dblk = (blockIdx.x >> 4) & 255;
    const int b    = blockIdx.x >> 12;
    const int tid  = threadIdx.x;
    const int n  = tid & 15;
    const int dg = tid >> 4;
    const int d  = dblk * 16 + dg;

    const float Av = -expf(alog[d * DS + n]);
    const size_t rowoff = (size_t)d * M_ + b * L_ + c * LC;
    const float* dtp = dt_t + rowoff;
    const float* xsp = xs_t + rowoff;
    const float* Bp  = Bt + (size_t)n * M_ + b * L_ + c * LC;

    float s = 0.f, dts = 0.f;
#pragma unroll 4
    for (int l = 0; l < LC; l += 4) {
        const float4 dt4 = *reinterpret_cast<const float4*>(dtp + l);
        const float4 x4  = *reinterpret_cast<const float4*>(xsp + l);
        const float4 b4  = *reinterpret_cast<const float4*>(Bp + l);
        s = fmaf(__expf(dt4.x * Av), s, dt4.x * b4.x * x4.x); dts += dt4.x;
        s = fmaf(__expf(dt4.y * Av), s, dt4.y * b4.y * x4.y); dts += dt4.y;
        s = fmaf(__expf(dt4.z * Av), s, dt4.z * b4.z * x4.z); dts += dt4.z;
        s = fmaf(__expf(dt4.w * Av), s, dt4.w * b4.w * x4.w); dts += dt4.w;
    }
    const size_t o = (size_t)c * NCHAIN + ((size_t)(b * DI + d)) * DS + n;
    sfin[o]  = s;
    aprod[o] = __expf(Av * dts);
}

// ---------------- scan phase 2 ----------------
__global__ __launch_bounds__(256)
void scan_phase2(const float* __restrict__ sfin, const float* __restrict__ aprod,
                 float* __restrict__ prefix) {
    const int t = blockIdx.x * 256 + threadIdx.x;
    float p = 0.f;
#pragma unroll
    for (int c = 0; c < NCH; ++c) {
        const size_t o = (size_t)c * NCHAIN + t;
        prefix[o] = p;
        p = fmaf(aprod[o], p, sfin[o]);
    }
}

// ---------------- scan phase 3 ----------------
__global__ __launch_bounds__(256)
void scan_phase3(const float* __restrict__ dt_t, const float* __restrict__ xs_t,
                 const float* __restrict__ Bt, const float* __restrict__ Ct,
                 const float* __restrict__ alog, const float* __restrict__ Dp,
                 const float* __restrict__ prefix, float* __restrict__ ybuf) {
    const int c    = blockIdx.x & 15;
    const int dblk = (blockIdx.x >> 4) & 255;
    const int b    = blockIdx.x >> 12;
    const int tid  = threadIdx.x;
    const int n  = tid & 15;
    const int dg = tid >> 4;
    const int d  = dblk * 16 + dg;

    const float Av = -expf(alog[d * DS + n]);
    const float Dv = Dp[d];
    float s = prefix[(size_t)c * NCHAIN + ((size_t)(b * DI + d)) * DS + n];

    const size_t rowoff = (size_t)d * M_ + b * L_ + c * LC;
    const float* dtp = dt_t + rowoff;
    const float* xsp = xs_t + rowoff;
    const float* Bp  = Bt + (size_t)n * M_ + b * L_ + c * LC;
    const float* Cp  = Ct + (size_t)n * M_ + b * L_ + c * LC;
    float* yout = ybuf + (size_t)(b * L_ + c * LC) * DI + d;

#pragma unroll 2
    for (int l = 0; l < LC; l += 4) {
        const float4 dt4 = *reinterpret_cast<const float4*>(dtp + l);
        const float4 x4  = *reinterpret_cast<const float4*>(xsp + l);
        const float4 b4  = *reinterpret_cast<const float4*>(Bp + l);
        const float4 c4  = *reinterpret_cast<const float4*>(Cp + l);
#pragma unroll
        for (int k = 0; k < 4; ++k) {
            const float dt = (k == 0) ? dt4.x : (k == 1) ? dt4.y : (k == 2) ? dt4.z : dt4.w;
            const float x  = (k == 0) ? x4.x  : (k == 1) ? x4.y  : (k == 2) ? x4.z  : x4.w;
            const float Bv = (k == 0) ? b4.x  : (k == 1) ? b4.y  : (k == 2) ? b4.z  : b4.w;
            const float Cv = (k == 0) ? c4.x  : (k == 1) ? c4.y  : (k == 2) ? c4.z  : c4.w;
            s = fmaf(__expf(dt * Av), s, dt * Bv * x);
            float contrib = s * Cv;
            contrib += __shfl_xor(contrib, 1);
            contrib += __shfl_xor(contrib, 2);
            contrib += __shfl_xor(contrib, 4);
            contrib += __shfl_xor(contrib, 8);
            if (n == 0) yout[(size_t)(l + k) * DI] = fmaf(x, Dv, contrib);
        }
    }
}

extern "C" void kernel_launch(void* const* d_in, const int* in_sizes, int n_in,
                              void* d_out, int out_size, void* d_ws, size_t ws_size,
                              hipStream_t stream) {
    const float* hs   = (const float*)d_in[0];
    const float* ipw  = (const float*)d_in[1];
    const float* cw   = (const float*)d_in[2];
    const float* cb   = (const float*)d_in[3];
    const float* xpw  = (const float*)d_in[4];
    const float* dpw  = (const float*)d_in[5];
    const float* dpb  = (const float*)d_in[6];
    const float* alog = (const float*)d_in[7];
    const float* Dp   = (const float*)d_in[8];
    const float* opw  = (const float*)d_in[9];
    float* out = (float*)d_out;

    float* ws    = (float*)d_ws;
    float* xz    = ws;                              // 16,777,216 f
    float* xs_t  = xz   + (size_t)16777216;         //  8,388,608 f
    float* xdbl  = xs_t + (size_t)8388608;          //    327,680 f
    float* ybuf  = xdbl + (size_t)327680;           //  8,388,608 f
    float* Bt    = ybuf + (size_t)8388608;          //     32,768 f
    float* Ct    = Bt   + (size_t)32768;            //     32,768 f
    float* R     = Ct   + (size_t)32768;

    // R: scan view
    float* dt_t  = R;                               // 8,388,608 f
    float* sfin  = R + (size_t)8388608;             // 2,097,152 f
    float* aprd  = sfin + (size_t)2097152;
    float* pref  = aprd + (size_t)2097152;
    float* pbuf  = dt_t;                            // splitk partials (5.24M f, dead before dt_t written)
    // R: phase-1 split view (dead after GEMM1)
    short* hs_hi  = (short*)R;
    short* hs_lo  = hs_hi + (size_t)M_ * DM;
    short* ipw_hi = hs_lo + (size_t)M_ * DM;
    short* ipw_lo = ipw_hi + (size_t)2 * DI * DM;
    // R: phase-2 split view (written after scan dies)
    short* yg_hi  = (short*)R;
    short* yg_lo  = yg_hi + (size_t)M_ * DI;
    short* opw_hi = yg_lo + (size_t)M_ * DI;
    short* opw_lo = opw_hi + (size_t)DM * DI;

    // 1) xz = hs @ in_proj_w^T  (split-bf16 MFMA, dbuf pipeline)
    split_bf16_kernel<<<(M_ * DM / 4 + 255) / 256, 256, 0, stream>>>(hs, hs_hi, hs_lo, M_ * DM / 4);
    split_bf16_kernel<<<(2 * DI * DM / 4 + 255) / 256, 256, 0, stream>>>(ipw, ipw_hi, ipw_lo, 2 * DI * DM / 4);
    gemm_mfma_split<128, 128, 7, 7><<<dim3(2 * DI / 128, M_ / 128), 256, 0, stream>>>(
        hs_hi, hs_lo, ipw_hi, ipw_lo, xz, M_, 2 * DI, DM);

    // 2) conv + silu -> xs_t directly (transposed)
    conv_silu_t<<<dim3(DI / 64, L_ / 32, B_), 256, 0, stream>>>(xz, cw, cb, xs_t);

    // 3) x_dbl = x_silu @ x_proj_w^T  (split-K from xs_t; reduce routes B/C)
    gemm_splitk_T<128, 32, 256><<<dim3(160 / 32, M_ / 128, 16), 256, 0, stream>>>(
        xs_t, xpw, DI, pbuf, 160, M_);
    reduce_bc<<<(M_ * 160 + 255) / 256, 256, 0, stream>>>(pbuf, xdbl, Bt, Ct);

    // 4) dt_t[d][bl] = softplus(dpw @ xdbl^T + 2*dpb)  (output born transposed)
    gemm_nt<128, 128, 2><<<dim3(M_ / 128, DI / 128), 256, 0, stream>>>(
        dpw, DR, xdbl, 160, dt_t, M_, DR, dpb);

    // 5) chunked scan
    scan_phase1<<<B_ * 256 * NCH, 256, 0, stream>>>(dt_t, xs_t, Bt, alog, sfin, aprd);
    scan_phase2<<<NCHAIN / 256, 256, 0, stream>>>(sfin, aprd, pref);
    scan_phase3<<<B_ * 256 * NCH, 256, 0, stream>>>(dt_t, xs_t, Bt, Ct, alog, Dp, pref, ybuf);

    // 6) out = (y*z) @ out_proj_w^T  (split-bf16 MFMA, dbuf pipeline)
    split_gate_kernel<<<(M_ * DI / 4) / 256, 256, 0, stream>>>(ybuf, xz, yg_hi, yg_lo);
    split_bf16_kernel<<<(DM * DI / 4 + 255) / 256, 256, 0, stream>>>(opw, opw_hi, opw_lo, DM * DI / 4);
    gemm_mfma_split<128, 64, 7, 6><<<dim3(DM / 64, M_ / 128), 256, 0, stream>>>(
        yg_hi, yg_lo, opw_hi, opw_lo, out, M_, DM, DI);
}

// Round 6
// 913.872 us; speedup vs baseline: 3.0183x; 1.0056x over previous
//
#include <hip/hip_runtime.h>
#include <math.h>
#include <stdint.h>

#define B_ 2
#define L_ 1024
#define DM 2048
#define DI 4096
#define DS 16
#define DR 128
#define M_ (B_*L_)
#define NCH 16
#define LC  64
#define NCHAIN (B_*DI*DS)

typedef __attribute__((ext_vector_type(8))) __bf16 bf16x8;
typedef __attribute__((ext_vector_type(4))) float f32x4;

__device__ __forceinline__ float softplus_f(float x) {
    return (x > 20.0f) ? x : log1pf(expf(x));
}
__device__ __forceinline__ float silu_f(float x) {
    return x / (1.0f + expf(-x));
}
__device__ __forceinline__ short f2bf_rn(float x) {
    uint32_t u = __builtin_bit_cast(uint32_t, x);
    u += 0x7FFFu + ((u >> 16) & 1u);
    return (short)(u >> 16);
}
__device__ __forceinline__ float bf2f(short h) {
    uint32_t u = ((uint32_t)(unsigned short)h) << 16;
    return __builtin_bit_cast(float, u);
}
__device__ __forceinline__ void gload16(const void* g, void* l) {
    __builtin_amdgcn_global_load_lds(
        (const __attribute__((address_space(1))) void*)g,
        (__attribute__((address_space(3))) void*)l, 16, 0, 0);
}

// ---------------- bf16 split kernels ----------------
__global__ __launch_bounds__(256)
void split_bf16_kernel(const float* __restrict__ in, short* __restrict__ hi,
                       short* __restrict__ lo, int n4) {
    const int i = blockIdx.x * 256 + threadIdx.x;
    if (i >= n4) return;
    const float4 v = reinterpret_cast<const float4*>(in)[i];
    short4 h, l;
    h.x = f2bf_rn(v.x); l.x = f2bf_rn(v.x - bf2f(h.x));
    h.y = f2bf_rn(v.y); l.y = f2bf_rn(v.y - bf2f(h.y));
    h.z = f2bf_rn(v.z); l.z = f2bf_rn(v.z - bf2f(h.z));
    h.w = f2bf_rn(v.w); l.w = f2bf_rn(v.w - bf2f(h.w));
    reinterpret_cast<short4*>(hi)[i] = h;
    reinterpret_cast<short4*>(lo)[i] = l;
}

__global__ __launch_bounds__(256)
void split_gate_kernel(const float* __restrict__ y, const float* __restrict__ xz,
                       short* __restrict__ hi, short* __restrict__ lo) {
    const int i = blockIdx.x * 256 + threadIdx.x;
    const int d4 = i & (DI / 4 - 1);
    const int bl = i >> 10;
    const float4 yv = reinterpret_cast<const float4*>(y)[i];
    const float4 zv = *reinterpret_cast<const float4*>(
        &xz[(size_t)bl * 2 * DI + DI + d4 * 4]);
    float4 v;
    v.x = yv.x * zv.x; v.y = yv.y * zv.y; v.z = yv.z * zv.z; v.w = yv.w * zv.w;
    short4 h, l;
    h.x = f2bf_rn(v.x); l.x = f2bf_rn(v.x - bf2f(h.x));
    h.y = f2bf_rn(v.y); l.y = f2bf_rn(v.y - bf2f(h.y));
    h.z = f2bf_rn(v.z); l.z = f2bf_rn(v.z - bf2f(h.z));
    h.w = f2bf_rn(v.w); l.w = f2bf_rn(v.w - bf2f(h.w));
    reinterpret_cast<short4*>(hi)[i] = h;
    reinterpret_cast<short4*>(lo)[i] = l;
}

// ---------------- 256x256 phase-split split-bf16 MFMA GEMM ----------------
// 512 threads (8 waves 2Mx4N), BK=32, 128KB LDS (dbuf x hi/lo x A/B),
// 4 phases per K-tile: {ds_read || gload_lds issue, s_barrier,
// setprio+24 MFMA, s_barrier}; single vmcnt(0) per K-tile with ~3 phases of
// slack. LDS chunk layout [kgc][row][16B] -> conflict-free ds_read_b128.
// SPLITK>1: blockIdx.z owns K-slice, writes partial C[z][M][N].
template<int SPLITK>
__global__ __launch_bounds__(512, 2)
void gemm256_split(const short* __restrict__ Ahi, const short* __restrict__ Alo,
                   const short* __restrict__ Bhi, const short* __restrict__ Blo,
                   float* __restrict__ C, int M, int N, int K) {
    __shared__ alignas(16) short sA[2][2][8192];   // [buf][hi/lo][256rows x 32k]
    __shared__ alignas(16) short sB[2][2][8192];

    const int tid  = threadIdx.x;
    const int wave = tid >> 6;
    const int lane = tid & 63;
    const int wm = wave >> 2, wn = wave & 3;       // 2 x 4 wave grid
    const int m0 = blockIdx.y * 256;
    const int n0 = blockIdx.x * 256;
    const int frow = lane & 15;
    const int kg   = lane >> 4;
    const int Ksl = K / SPLITK;
    const int k0  = blockIdx.z * Ksl;
    const int NT  = Ksl / 32;
    float* Cz = C + (size_t)blockIdx.z * M * N;

    // per-thread staging source precompute: chunk li in [0,1024), 2 per thread
    size_t gA[2], gB[2];
    int lio[2];
#pragma unroll
    for (int r = 0; r < 2; ++r) {
        const int li = r * 512 + tid;
        lio[r] = li;
        const int row = li & 255, kgc = li >> 8;
        gA[r] = (size_t)(m0 + row) * K + k0 + kgc * 8;
        gB[r] = (size_t)(n0 + row) * K + k0 + kgc * 8;
    }

    auto stageA = [&](int buf, int kt) {
#pragma unroll
        for (int r = 0; r < 2; ++r) {
            gload16(Ahi + gA[r] + kt, &sA[buf][0][lio[r] << 3]);
            gload16(Alo + gA[r] + kt, &sA[buf][1][lio[r] << 3]);
        }
    };
    auto stageB = [&](int buf, int kt) {
#pragma unroll
        for (int r = 0; r < 2; ++r) {
            gload16(Bhi + gB[r] + kt, &sB[buf][0][lio[r] << 3]);
            gload16(Blo + gB[r] + kt, &sB[buf][1][lio[r] << 3]);
        }
    };

    f32x4 acc[8][4];
#pragma unroll
    for (int i = 0; i < 8; ++i)
#pragma unroll
        for (int j = 0; j < 4; ++j) acc[i][j] = (f32x4){0.f, 0.f, 0.f, 0.f};

    bf16x8 ah[4], al[4], bh[4], bl[4];

    stageA(0, 0);
    stageB(0, 0);
    asm volatile("s_waitcnt vmcnt(0)" ::: "memory");
    __builtin_amdgcn_s_barrier();

    int cur = 0;
    for (int t = 0; t < NT; ++t) {
        const int ktn = (t + 1) * 32;      // relative to k0
        const bool pf = (t + 1 < NT);

        // ---- phase 0: read A-half0 + B-half0; issue next A loads
#pragma unroll
        for (int i = 0; i < 4; ++i) {
            const int ra = wm * 128 + i * 16 + frow;
            ah[i] = *reinterpret_cast<const bf16x8*>(&sA[cur][0][(kg * 256 + ra) << 3]);
            al[i] = *reinterpret_cast<const bf16x8*>(&sA[cur][1][(kg * 256 + ra) << 3]);
        }
#pragma unroll
        for (int j = 0; j < 2; ++j) {
            const int rb = wn * 64 + j * 16 + frow;
            bh[j] = *reinterpret_cast<const bf16x8*>(&sB[cur][0][(kg * 256 + rb) << 3]);
            bl[j] = *reinterpret_cast<const bf16x8*>(&sB[cur][1][(kg * 256 + rb) << 3]);
        }
        if (pf) stageA(cur ^ 1, ktn);
        __builtin_amdgcn_s_barrier();
        __builtin_amdgcn_s_setprio(1);
#pragma unroll
        for (int i = 0; i < 4; ++i)
#pragma unroll
            for (int j = 0; j < 2; ++j) {
                acc[i][j] = __builtin_amdgcn_mfma_f32_16x16x32_bf16(ah[i], bh[j], acc[i][j], 0, 0, 0);
                acc[i][j] = __builtin_amdgcn_mfma_f32_16x16x32_bf16(ah[i], bl[j], acc[i][j], 0, 0, 0);
                acc[i][j] = __builtin_amdgcn_mfma_f32_16x16x32_bf16(al[i], bh[j], acc[i][j], 0, 0, 0);
            }
        __builtin_amdgcn_s_setprio(0);
        __builtin_amdgcn_s_barrier();

        // ---- phase 1: read B-half1; issue next B loads
#pragma unroll
        for (int j = 2; j < 4; ++j) {
            const int rb = wn * 64 + j * 16 + frow;
            bh[j] = *reinterpret_cast<const bf16x8*>(&sB[cur][0][(kg * 256 + rb) << 3]);
            bl[j] = *reinterpret_cast<const bf16x8*>(&sB[cur][1][(kg * 256 + rb) << 3]);
        }
        if (pf) stageB(cur ^ 1, ktn);
        __builtin_amdgcn_s_barrier();
        __builtin_amdgcn_s_setprio(1);
#pragma unroll
        for (int i = 0; i < 4; ++i)
#pragma unroll
            for (int j = 2; j < 4; ++j) {
                acc[i][j] = __builtin_amdgcn_mfma_f32_16x16x32_bf16(ah[i], bh[j], acc[i][j], 0, 0, 0);
                acc[i][j] = __builtin_amdgcn_mfma_f32_16x16x32_bf16(ah[i], bl[j], acc[i][j], 0, 0, 0);
                acc[i][j] = __builtin_amdgcn_mfma_f32_16x16x32_bf16(al[i], bh[j], acc[i][j], 0, 0, 0);
            }
        __builtin_amdgcn_s_setprio(0);
        __builtin_amdgcn_s_barrier();

        // ---- phase 2: read A-half1 (reuse regs)
#pragma unroll
        for (int i = 0; i < 4; ++i) {
            const int ra = wm * 128 + (4 + i) * 16 + frow;
            ah[i] = *reinterpret_cast<const bf16x8*>(&sA[cur][0][(kg * 256 + ra) << 3]);
            al[i] = *reinterpret_cast<const bf16x8*>(&sA[cur][1][(kg * 256 + ra) << 3]);
        }
        __builtin_amdgcn_s_barrier();
        __builtin_amdgcn_s_setprio(1);
#pragma unroll
        for (int i = 0; i < 4; ++i)
#pragma unroll
            for (int j = 0; j < 2; ++j) {
                acc[4 + i][j] = __builtin_amdgcn_mfma_f32_16x16x32_bf16(ah[i], bh[j], acc[4 + i][j], 0, 0, 0);
                acc[4 + i][j] = __builtin_amdgcn_mfma_f32_16x16x32_bf16(ah[i], bl[j], acc[4 + i][j], 0, 0, 0);
                acc[4 + i][j] = __builtin_amdgcn_mfma_f32_16x16x32_bf16(al[i], bh[j], acc[4 + i][j], 0, 0, 0);
            }
        __builtin_amdgcn_s_setprio(0);
        __builtin_amdgcn_s_barrier();

        // ---- phase 3: MFMA only; then drain next-tile loads (issued 2-3 phases ago)
        __builtin_amdgcn_s_setprio(1);
#pragma unroll
        for (int i = 0; i < 4; ++i)
#pragma unroll
            for (int j = 2; j < 4; ++j) {
                acc[4 + i][j] = __builtin_amdgcn_mfma_f32_16x16x32_bf16(ah[i], bh[j], acc[4 + i][j], 0, 0, 0);
                acc[4 + i][j] = __builtin_amdgcn_mfma_f32_16x16x32_bf16(ah[i], bl[j], acc[4 + i][j], 0, 0, 0);
                acc[4 + i][j] = __builtin_amdgcn_mfma_f32_16x16x32_bf16(al[i], bh[j], acc[4 + i][j], 0, 0, 0);
            }
        __builtin_amdgcn_s_setprio(0);
        asm volatile("s_waitcnt vmcnt(0)" ::: "memory");
        __builtin_amdgcn_s_barrier();
        cur ^= 1;
    }

    const int crow0 = m0 + wm * 128 + (lane >> 4) * 4;
    const int ccol0 = n0 + wn * 64 + (lane & 15);
#pragma unroll
    for (int mi = 0; mi < 8; ++mi)
#pragma unroll
        for (int ni = 0; ni < 4; ++ni)
#pragma unroll
            for (int r = 0; r < 4; ++r)
                Cz[(size_t)(crow0 + mi * 16 + r) * N + ccol0 + ni * 16] = acc[mi][ni][r];
}

// reduce 4 split-K partials (vectorized)
__global__ __launch_bounds__(256)
void reduce4_kernel(const float* __restrict__ p, float* __restrict__ o, int n4) {
    const int i = blockIdx.x * 256 + threadIdx.x;
    if (i >= n4) return;
    const int n = n4 * 4;
    const float4 a = reinterpret_cast<const float4*>(p)[i];
    const float4 b = *reinterpret_cast<const float4*>(&p[(size_t)n + i * 4]);
    const float4 c = *reinterpret_cast<const float4*>(&p[(size_t)2 * n + i * 4]);
    const float4 d = *reinterpret_cast<const float4*>(&p[(size_t)3 * n + i * 4]);
    float4 s;
    s.x = (a.x + b.x) + (c.x + d.x);
    s.y = (a.y + b.y) + (c.y + d.y);
    s.z = (a.z + b.z) + (c.z + d.z);
    s.w = (a.w + b.w) + (c.w + d.w);
    reinterpret_cast<float4*>(o)[i] = s;
}

// ---------------- fp32 vector GEMM ----------------
// MODE 0: plain. MODE 2: C = softplus(acc + 2*bias[m])  (bias per ROW)
template<int BM, int BN, int MODE>
__global__ __launch_bounds__(256)
void gemm_nt(const float* __restrict__ A, int lda,
             const float* __restrict__ W, int ldw,
             float* __restrict__ C, int ldc,
             int K, const float* __restrict__ bias) {
    constexpr int BK = 16;
    constexpr int TM = BM / 16;
    constexpr int TN = BN / 16;
    __shared__ float As[BK][BM];
    __shared__ float Ws[BK][BN];
    const int tid = threadIdx.x;
    const int tx = tid & 15;
    const int ty = tid >> 4;
    const int m0 = blockIdx.y * BM;
    const int n0 = blockIdx.x * BN;

    float acc[TM][TN];
#pragma unroll
    for (int i = 0; i < TM; ++i)
#pragma unroll
        for (int j = 0; j < TN; ++j) acc[i][j] = 0.0f;

    for (int kt = 0; kt < K; kt += BK) {
        for (int v = tid; v < BM * 4; v += 256) {
            const int row = v >> 2;
            const int kq  = (v & 3) << 2;
            const float4 t = *reinterpret_cast<const float4*>(
                &A[(size_t)(m0 + row) * lda + kt + kq]);
            As[kq + 0][row] = t.x; As[kq + 1][row] = t.y;
            As[kq + 2][row] = t.z; As[kq + 3][row] = t.w;
        }
        for (int v = tid; v < BN * 4; v += 256) {
            const int row = v >> 2;
            const int kq  = (v & 3) << 2;
            const float4 t = *reinterpret_cast<const float4*>(
                &W[(size_t)(n0 + row) * ldw + kt + kq]);
            Ws[kq + 0][row] = t.x; Ws[kq + 1][row] = t.y;
            Ws[kq + 2][row] = t.z; Ws[kq + 3][row] = t.w;
        }
        __syncthreads();
#pragma unroll
        for (int kk = 0; kk < BK; ++kk) {
            float a[TM], w[TN];
#pragma unroll
            for (int i = 0; i < TM; ++i) a[i] = As[kk][ty * TM + i];
#pragma unroll
            for (int j = 0; j < TN; ++j) w[j] = Ws[kk][tx * TN + j];
#pragma unroll
            for (int i = 0; i < TM; ++i)
#pragma unroll
                for (int j = 0; j < TN; ++j)
                    acc[i][j] = fmaf(a[i], w[j], acc[i][j]);
        }
        __syncthreads();
    }

#pragma unroll
    for (int i = 0; i < TM; ++i) {
        const size_t rowoff = (size_t)(m0 + ty * TM + i) * ldc + n0 + tx * TN;
        float bm = 0.f;
        if constexpr (MODE == 2) bm = 2.0f * bias[m0 + ty * TM + i];
#pragma unroll
        for (int j = 0; j < TN; ++j) {
            float v = acc[i][j];
            if constexpr (MODE == 2) v = softplus_f(v + bm);
            C[rowoff + j] = v;
        }
    }
}

// ---------------- split-K fp32 GEMM, A read from transposed xs_t ----------
template<int BM, int BN, int KSL>
__global__ __launch_bounds__(256)
void gemm_splitk_T(const float* __restrict__ At,
                   const float* __restrict__ W, int ldw,
                   float* __restrict__ pbuf, int ldc, int M) {
    constexpr int BK = 16;
    constexpr int TM = BM / 16;
    constexpr int TN = BN / 16;
    __shared__ float As[BK][BM];
    __shared__ float Ws[BK][BN];
    const int tid = threadIdx.x;
    const int tx = tid & 15;
    const int ty = tid >> 4;
    const int m0 = blockIdx.y * BM;
    const int n0 = blockIdx.x * BN;
    const int k0 = blockIdx.z * KSL;

    float acc[TM][TN];
#pragma unroll
    for (int i = 0; i < TM; ++i)
#pragma unroll
        for (int j = 0; j < TN; ++j) acc[i][j] = 0.0f;

    for (int kt = k0; kt < k0 + KSL; kt += BK) {
        for (int v = tid; v < BK * BM / 4; v += 256) {
            const int kk = v >> 5;
            const int m4 = (v & 31) << 2;
            *reinterpret_cast<float4*>(&As[kk][m4]) =
                *reinterpret_cast<const float4*>(&At[(size_t)(kt + kk) * M + m0 + m4]);
        }
        for (int v = tid; v < BN * 4; v += 256) {
            const int row = v >> 2;
            const int kq  = (v & 3) << 2;
            const float4 t = *reinterpret_cast<const float4*>(
                &W[(size_t)(n0 + row) * ldw + kt + kq]);
            Ws[kq + 0][row] = t.x; Ws[kq + 1][row] = t.y;
            Ws[kq + 2][row] = t.z; Ws[kq + 3][row] = t.w;
        }
        __syncthreads();
#pragma unroll
        for (int kk = 0; kk < BK; ++kk) {
            float a[TM], w[TN];
#pragma unroll
            for (int i = 0; i < TM; ++i) a[i] = As[kk][ty * TM + i];
#pragma unroll
            for (int j = 0; j < TN; ++j) w[j] = Ws[kk][tx * TN + j];
#pragma unroll
            for (int i = 0; i < TM; ++i)
#pragma unroll
                for (int j = 0; j < TN; ++j)
                    acc[i][j] = fmaf(a[i], w[j], acc[i][j]);
        }
        __syncthreads();
    }

    float* outp = pbuf + (size_t)blockIdx.z * M * ldc;
#pragma unroll
    for (int i = 0; i < TM; ++i) {
        const size_t rowoff = (size_t)(m0 + ty * TM + i) * ldc + n0 + tx * TN;
#pragma unroll
        for (int j = 0; j < TN; ++j) outp[rowoff + j] = acc[i][j];
    }
}

// reduce split-K partials; route dt-rank cols to xdbl, B/C cols to Bt/Ct
__global__ __launch_bounds__(256)
void reduce_bc(const float* __restrict__ pbuf, float* __restrict__ xdbl,
               float* __restrict__ Bt, float* __restrict__ Ct) {
    const int i = blockIdx.x * 256 + threadIdx.x;
    if (i >= M_ * 160) return;
    float s = 0.f;
#pragma unroll
    for (int z = 0; z < 16; ++z) s += pbuf[(size_t)z * M_ * 160 + i];
    const int bl = i / 160;
    const int c  = i - bl * 160;
    if (c < 128)      xdbl[i] = s;
    else if (c < 144) Bt[(size_t)(c - 128) * M_ + bl] = s;
    else              Ct[(size_t)(c - 144) * M_ + bl] = s;
}

// ---------------- conv + bias + silu, transposed output ----------------
__global__ __launch_bounds__(256)
void conv_silu_t(const float* __restrict__ xz, const float* __restrict__ cw,
                 const float* __restrict__ cb, float* __restrict__ xs_t) {
    __shared__ float tin[35][64];
    __shared__ float tout[64][33];
    const int d0 = blockIdx.x * 64;
    const int l0 = blockIdx.y * 32;
    const int b  = blockIdx.z;
    const int tid = threadIdx.x;

    for (int v = tid; v < 35 * 16; v += 256) {
        const int row = v >> 4;
        const int c4  = (v & 15) << 2;
        const int l = l0 - 3 + row;
        float4 t = {0.f, 0.f, 0.f, 0.f};
        if (l >= 0)
            t = *reinterpret_cast<const float4*>(
                &xz[(size_t)(b * L_ + l) * 2 * DI + d0 + c4]);
        *reinterpret_cast<float4*>(&tin[row][c4]) = t;
    }
    __syncthreads();

    const int dl = tid & 63;
    const int lq = tid >> 6;
    const float w0 = cw[(d0 + dl) * 4 + 0], w1 = cw[(d0 + dl) * 4 + 1];
    const float w2 = cw[(d0 + dl) * 4 + 2], w3 = cw[(d0 + dl) * 4 + 3];
    const float bias = cb[d0 + dl];
#pragma unroll
    for (int li = lq; li < 32; li += 4) {
        const float s = bias + tin[li][dl] * w0 + tin[li + 1][dl] * w1
                      + tin[li + 2][dl] * w2 + tin[li + 3][dl] * w3;
        tout[dl][li] = silu_f(s);
    }
    __syncthreads();

    for (int v = tid; v < 64 * 8; v += 256) {
        const int row = v >> 3;
        const int c4  = (v & 7) << 2;
        float4 t;
        t.x = tout[row][c4 + 0]; t.y = tout[row][c4 + 1];
        t.z = tout[row][c4 + 2]; t.w = tout[row][c4 + 3];
        *reinterpret_cast<float4*>(&xs_t[(size_t)(d0 + row) * M_ + b * L_ + l0 + c4]) = t;
    }
}

// ---------------- scan phase 1 ----------------
__global__ __launch_bounds__(256)
void scan_phase1(const float* __restrict__ dt_t, const float* __restrict__ xs_t,
                 const float* __restrict__ Bt, const float* __restrict__ alog,
                 float* __restrict__ sfin, float* __restrict__ aprod) {
    const int c    = blockIdx.x & 15;
    const int dblk = (blockIdx.x >> 4) & 255;
    const int b    = blockIdx.x >> 12;
    const int tid  = threadIdx.x;
    const int n  = tid & 15;
    const int dg = tid >> 4;
    const int d  = dblk * 16 + dg;

    const float Av = -expf(alog[d * DS + n]);
    const size_t rowoff = (size_t)d * M_ + b * L_ + c * LC;
    const float* dtp = dt_t + rowoff;
    const float* xsp = xs_t + rowoff;
    const float* Bp  = Bt + (size_t)n * M_ + b * L_ + c * LC;

    float s = 0.f, dts = 0.f;
#pragma unroll 4
    for (int l = 0; l < LC; l += 4) {
        const float4 dt4 = *reinterpret_cast<const float4*>(dtp + l);
        const float4 x4  = *reinterpret_cast<const float4*>(xsp + l);
        const float4 b4  = *reinterpret_cast<const float4*>(Bp + l);
        s = fmaf(__expf(dt4.x * Av), s, dt4.x * b4.x * x4.x); dts += dt4.x;
        s = fmaf(__expf(dt4.y * Av), s, dt4.y * b4.y * x4.y); dts += dt4.y;
        s = fmaf(__expf(dt4.z * Av), s, dt4.z * b4.z * x4.z); dts += dt4.z;
        s = fmaf(__expf(dt4.w * Av), s, dt4.w * b4.w * x4.w); dts += dt4.w;
    }
    const size_t o = (size_t)c * NCHAIN + ((size_t)(b * DI + d)) * DS + n;
    sfin[o]  = s;
    aprod[o] = __expf(Av * dts);
}

// ---------------- scan phase 2 ----------------
__global__ __launch_bounds__(256)
void scan_phase2(const float* __restrict__ sfin, const float* __restrict__ aprod,
                 float* __restrict__ prefix) {
    const int t = blockIdx.x * 256 + threadIdx.x;
    float p = 0.f;
#pragma unroll
    for (int c = 0; c < NCH; ++c) {
        const size_t o = (size_t)c * NCHAIN + t;
        prefix[o] = p;
        p = fmaf(aprod[o], p, sfin[o]);
    }
}

// ---------------- scan phase 3 ----------------
__global__ __launch_bounds__(256)
void scan_phase3(const float* __restrict__ dt_t, const float* __restrict__ xs_t,
                 const float* __restrict__ Bt, const float* __restrict__ Ct,
                 const float* __restrict__ alog, const float* __restrict__ Dp,
                 const float* __restrict__ prefix, float* __restrict__ ybuf) {
    const int c    = blockIdx.x & 15;
    const int dblk = (blockIdx.x >> 4) & 255;
    const int b    = blockIdx.x >> 12;
    const int tid  = threadIdx.x;
    const int n  = tid & 15;
    const int dg = tid >> 4;
    const int d  = dblk * 16 + dg;

    const float Av = -expf(alog[d * DS + n]);
    const float Dv = Dp[d];
    float s = prefix[(size_t)c * NCHAIN + ((size_t)(b * DI + d)) * DS + n];

    const size_t rowoff = (size_t)d * M_ + b * L_ + c * LC;
    const float* dtp = dt_t + rowoff;
    const float* xsp = xs_t + rowoff;
    const float* Bp  = Bt + (size_t)n * M_ + b * L_ + c * LC;
    const float* Cp  = Ct + (size_t)n * M_ + b * L_ + c * LC;
    float* yout = ybuf + (size_t)(b * L_ + c * LC) * DI + d;

#pragma unroll 2
    for (int l = 0; l < LC; l += 4) {
        const float4 dt4 = *reinterpret_cast<const float4*>(dtp + l);
        const float4 x4  = *reinterpret_cast<const float4*>(xsp + l);
        const float4 b4  = *reinterpret_cast<const float4*>(Bp + l);
        const float4 c4  = *reinterpret_cast<const float4*>(Cp + l);
#pragma unroll
        for (int k = 0; k < 4; ++k) {
            const float dt = (k == 0) ? dt4.x : (k == 1) ? dt4.y : (k == 2) ? dt4.z : dt4.w;
            const float x  = (k == 0) ? x4.x  : (k == 1) ? x4.y  : (k == 2) ? x4.z  : x4.w;
            const float Bv = (k == 0) ? b4.x  : (k == 1) ? b4.y  : (k == 2) ? b4.z  : b4.w;
            const float Cv = (k == 0) ? c4.x  : (k == 1) ? c4.y  : (k == 2) ? c4.z  : c4.w;
            s = fmaf(__expf(dt * Av), s, dt * Bv * x);
            float contrib = s * Cv;
            contrib += __shfl_xor(contrib, 1);
            contrib += __shfl_xor(contrib, 2);
            contrib += __shfl_xor(contrib, 4);
            contrib += __shfl_xor(contrib, 8);
            if (n == 0) yout[(size_t)(l + k) * DI] = fmaf(x, Dv, contrib);
        }
    }
}

extern "C" void kernel_launch(void* const* d_in, const int* in_sizes, int n_in,
                              void* d_out, int out_size, void* d_ws, size_t ws_size,
                              hipStream_t stream) {
    const float* hs   = (const float*)d_in[0];
    const float* ipw  = (const float*)d_in[1];
    const float* cw   = (const float*)d_in[2];
    const float* cb   = (const float*)d_in[3];
    const float* xpw  = (const float*)d_in[4];
    const float* dpw  = (const float*)d_in[5];
    const float* dpb  = (const float*)d_in[6];
    const float* alog = (const float*)d_in[7];
    const float* Dp   = (const float*)d_in[8];
    const float* opw  = (const float*)d_in[9];
    float* out = (float*)d_out;

    float* ws    = (float*)d_ws;
    float* xz    = ws;                              // 16,777,216 f
    float* xs_t  = xz   + (size_t)16777216;         //  8,388,608 f
    float* xdbl  = xs_t + (size_t)8388608;          //    327,680 f
    float* ybuf  = xdbl + (size_t)327680;           //  8,388,608 f
    float* Bt    = ybuf + (size_t)8388608;          //     32,768 f
    float* Ct    = Bt   + (size_t)32768;            //     32,768 f
    float* R     = Ct   + (size_t)32768;

    // R: scan view
    float* dt_t  = R;                               // 8,388,608 f
    float* sfin  = R + (size_t)8388608;             // 2,097,152 f
    float* aprd  = sfin + (size_t)2097152;
    float* pref  = aprd + (size_t)2097152;
    float* pbuf  = dt_t;                            // splitk partials (x_proj)
    // R: phase-1 split view (dead after GEMM1)
    short* hs_hi  = (short*)R;
    short* hs_lo  = hs_hi + (size_t)M_ * DM;
    short* ipw_hi = hs_lo + (size_t)M_ * DM;
    short* ipw_lo = ipw_hi + (size_t)2 * DI * DM;
    // R: phase-2 split view (written after scan dies)
    short* yg_hi  = (short*)R;
    short* yg_lo  = yg_hi + (size_t)M_ * DI;
    short* opw_hi = yg_lo + (size_t)M_ * DI;
    short* opw_lo = opw_hi + (size_t)DM * DI;
    // GEMM6 split-K partials: xz region (dead after split_gate)
    float* pbuf6  = xz;                             // 4 * 2048 * 2048 f

    // 1) xz = hs @ in_proj_w^T  (split-bf16, 256x256 phase-split MFMA)
    split_bf16_kernel<<<(M_ * DM / 4 + 255) / 256, 256, 0, stream>>>(hs, hs_hi, hs_lo, M_ * DM / 4);
    split_bf16_kernel<<<(2 * DI * DM / 4 + 255) / 256, 256, 0, stream>>>(ipw, ipw_hi, ipw_lo, 2 * DI * DM / 4);
    gemm256_split<1><<<dim3(2 * DI / 256, M_ / 256, 1), 512, 0, stream>>>(
        hs_hi, hs_lo, ipw_hi, ipw_lo, xz, M_, 2 * DI, DM);

    // 2) conv + silu -> xs_t directly (transposed)
    conv_silu_t<<<dim3(DI / 64, L_ / 32, B_), 256, 0, stream>>>(xz, cw, cb, xs_t);

    // 3) x_dbl = x_silu @ x_proj_w^T  (split-K from xs_t; reduce routes B/C)
    gemm_splitk_T<128, 32, 256><<<dim3(160 / 32, M_ / 128, 16), 256, 0, stream>>>(
        xs_t, xpw, DI, pbuf, 160, M_);
    reduce_bc<<<(M_ * 160 + 255) / 256, 256, 0, stream>>>(pbuf, xdbl, Bt, Ct);

    // 4) dt_t[d][bl] = softplus(dpw @ xdbl^T + 2*dpb)
    gemm_nt<128, 128, 2><<<dim3(M_ / 128, DI / 128), 256, 0, stream>>>(
        dpw, DR, xdbl, 160, dt_t, M_, DR, dpb);

    // 5) chunked scan
    scan_phase1<<<B_ * 256 * NCH, 256, 0, stream>>>(dt_t, xs_t, Bt, alog, sfin, aprd);
    scan_phase2<<<NCHAIN / 256, 256, 0, stream>>>(sfin, aprd, pref);
    scan_phase3<<<B_ * 256 * NCH, 256, 0, stream>>>(dt_t, xs_t, Bt, Ct, alog, Dp, pref, ybuf);

    // 6) out = (y*z) @ out_proj_w^T  (split-bf16, 256x256 split-K x4)
    split_gate_kernel<<<(M_ * DI / 4) / 256, 256, 0, stream>>>(ybuf, xz, yg_hi, yg_lo);
    split_bf16_kernel<<<(DM * DI / 4 + 255) / 256, 256, 0, stream>>>(opw, opw_hi, opw_lo, DM * DI / 4);
    gemm256_split<4><<<dim3(DM / 256, M_ / 256, 4), 512, 0, stream>>>(
        yg_hi, yg_lo, opw_hi, opw_lo, pbuf6, M_, DM, DI);
    reduce4_kernel<<<(M_ * DM / 4 + 255) / 256, 256, 0, stream>>>(pbuf6, out, M_ * DM / 4);
}

// Round 7
// 888.764 us; speedup vs baseline: 3.1036x; 1.0283x over previous
//
#include <hip/hip_runtime.h>
#include <math.h>
#include <stdint.h>

#define B_ 2
#define L_ 1024
#define DM 2048
#define DI 4096
#define DS 16
#define DR 128
#define M_ (B_*L_)
#define NCH 16
#define LC  64
#define NCHAIN (B_*DI*DS)

typedef __attribute__((ext_vector_type(8))) __bf16 bf16x8;
typedef __attribute__((ext_vector_type(4))) float f32x4;

__device__ __forceinline__ float softplus_f(float x) {
    return (x > 20.0f) ? x : log1pf(expf(x));
}
__device__ __forceinline__ float silu_f(float x) {
    return x / (1.0f + expf(-x));
}
__device__ __forceinline__ short f2bf_rn(float x) {
    uint32_t u = __builtin_bit_cast(uint32_t, x);
    u += 0x7FFFu + ((u >> 16) & 1u);
    return (short)(u >> 16);
}
__device__ __forceinline__ float bf2f(short h) {
    uint32_t u = ((uint32_t)(unsigned short)h) << 16;
    return __builtin_bit_cast(float, u);
}
__device__ __forceinline__ void gload16(const void* g, void* l) {
    __builtin_amdgcn_global_load_lds(
        (const __attribute__((address_space(1))) void*)g,
        (__attribute__((address_space(3))) void*)l, 16, 0, 0);
}

// ---------------- bf16 split kernels ----------------
__global__ __launch_bounds__(256)
void split_bf16_kernel(const float* __restrict__ in, short* __restrict__ hi,
                       short* __restrict__ lo, int n4) {
    const int i = blockIdx.x * 256 + threadIdx.x;
    if (i >= n4) return;
    const float4 v = reinterpret_cast<const float4*>(in)[i];
    short4 h, l;
    h.x = f2bf_rn(v.x); l.x = f2bf_rn(v.x - bf2f(h.x));
    h.y = f2bf_rn(v.y); l.y = f2bf_rn(v.y - bf2f(h.y));
    h.z = f2bf_rn(v.z); l.z = f2bf_rn(v.z - bf2f(h.z));
    h.w = f2bf_rn(v.w); l.w = f2bf_rn(v.w - bf2f(h.w));
    reinterpret_cast<short4*>(hi)[i] = h;
    reinterpret_cast<short4*>(lo)[i] = l;
}

__global__ __launch_bounds__(256)
void split_gate_kernel(const float* __restrict__ y, const float* __restrict__ xz,
                       short* __restrict__ hi, short* __restrict__ lo) {
    const int i = blockIdx.x * 256 + threadIdx.x;
    const int d4 = i & (DI / 4 - 1);
    const int bl = i >> 10;
    const float4 yv = reinterpret_cast<const float4*>(y)[i];
    const float4 zv = *reinterpret_cast<const float4*>(
        &xz[(size_t)bl * 2 * DI + DI + d4 * 4]);
    float4 v;
    v.x = yv.x * zv.x; v.y = yv.y * zv.y; v.z = yv.z * zv.z; v.w = yv.w * zv.w;
    short4 h, l;
    h.x = f2bf_rn(v.x); l.x = f2bf_rn(v.x - bf2f(h.x));
    h.y = f2bf_rn(v.y); l.y = f2bf_rn(v.y - bf2f(h.y));
    h.z = f2bf_rn(v.z); l.z = f2bf_rn(v.z - bf2f(h.z));
    h.w = f2bf_rn(v.w); l.w = f2bf_rn(v.w - bf2f(h.w));
    reinterpret_cast<short4*>(hi)[i] = h;
    reinterpret_cast<short4*>(lo)[i] = l;
}

// ---------------- 256x256 phase-split split-bf16 MFMA GEMM ----------------
// 512 threads (8 waves 2Mx4N), BK=32, 128KB LDS (dbuf x hi/lo x A/B).
// Depth-2 prefetch with COUNTED vmcnt: within tile t, sB[cur] is dead after
// phase-1 reads, sA[cur] after phase-2 reads -> phase 2 issues B(t+2) and
// phase 3 issues A(t+2) into buf[cur]. End-of-tile waits vmcnt(8): the 8
// newest (t+2) loads stay in flight; the wait covers t+1's loads issued
// 4-6 phases earlier. Never drains to 0 in the main loop (T3+T4).
// LDS chunk layout [kgc][row][16B] -> conflict-free ds_read_b128 (T2-equiv).
template<int SPLITK>
__global__ __launch_bounds__(512, 2)
void gemm256_split(const short* __restrict__ Ahi, const short* __restrict__ Alo,
                   const short* __restrict__ Bhi, const short* __restrict__ Blo,
                   float* __restrict__ C, int M, int N, int K) {
    __shared__ alignas(16) short sA[2][2][8192];   // [buf][hi/lo][256rows x 32k]
    __shared__ alignas(16) short sB[2][2][8192];

    const int tid  = threadIdx.x;
    const int wave = tid >> 6;
    const int lane = tid & 63;
    const int wm = wave >> 2, wn = wave & 3;       // 2 x 4 wave grid
    const int m0 = blockIdx.y * 256;
    const int n0 = blockIdx.x * 256;
    const int frow = lane & 15;
    const int kg   = lane >> 4;
    const int Ksl = K / SPLITK;
    const int k0  = blockIdx.z * Ksl;
    const int NT  = Ksl / 32;
    float* Cz = C + (size_t)blockIdx.z * M * N;

    // per-thread staging source precompute: chunk li in [0,1024), 2 per thread
    size_t gA[2], gB[2];
    int lio[2];
#pragma unroll
    for (int r = 0; r < 2; ++r) {
        const int li = r * 512 + tid;
        lio[r] = li;
        const int row = li & 255, kgc = li >> 8;
        gA[r] = (size_t)(m0 + row) * K + k0 + kgc * 8;
        gB[r] = (size_t)(n0 + row) * K + k0 + kgc * 8;
    }

    auto stageA = [&](int buf, int kt) {       // 4 loads/thread
#pragma unroll
        for (int r = 0; r < 2; ++r) {
            gload16(Ahi + gA[r] + kt, &sA[buf][0][lio[r] << 3]);
            gload16(Alo + gA[r] + kt, &sA[buf][1][lio[r] << 3]);
        }
    };
    auto stageB = [&](int buf, int kt) {       // 4 loads/thread
#pragma unroll
        for (int r = 0; r < 2; ++r) {
            gload16(Bhi + gB[r] + kt, &sB[buf][0][lio[r] << 3]);
            gload16(Blo + gB[r] + kt, &sB[buf][1][lio[r] << 3]);
        }
    };

    f32x4 acc[8][4];
#pragma unroll
    for (int i = 0; i < 8; ++i)
#pragma unroll
        for (int j = 0; j < 4; ++j) acc[i][j] = (f32x4){0.f, 0.f, 0.f, 0.f};

    bf16x8 ah[4], al[4], bh[4], bl[4];

    // prologue: stage tiles 0 and 1; wait for tile 0 only (tile 1 in flight)
    stageA(0, 0);
    stageB(0, 0);
    if (NT > 1) {
        stageA(1, 32);
        stageB(1, 32);
        asm volatile("s_waitcnt vmcnt(8)" ::: "memory");
    } else {
        asm volatile("s_waitcnt vmcnt(0)" ::: "memory");
    }
    __builtin_amdgcn_s_barrier();

    int cur = 0;
    for (int t = 0; t < NT; ++t) {
        const bool pf2 = (t + 2 < NT);
        const int kt2 = (t + 2) * 32;

        // ---- phase 0: read A-half0 + B-half0; MFMA quadrant (0..3)x(0..1)
#pragma unroll
        for (int i = 0; i < 4; ++i) {
            const int ra = wm * 128 + i * 16 + frow;
            ah[i] = *reinterpret_cast<const bf16x8*>(&sA[cur][0][(kg * 256 + ra) << 3]);
            al[i] = *reinterpret_cast<const bf16x8*>(&sA[cur][1][(kg * 256 + ra) << 3]);
        }
#pragma unroll
        for (int j = 0; j < 2; ++j) {
            const int rb = wn * 64 + j * 16 + frow;
            bh[j] = *reinterpret_cast<const bf16x8*>(&sB[cur][0][(kg * 256 + rb) << 3]);
            bl[j] = *reinterpret_cast<const bf16x8*>(&sB[cur][1][(kg * 256 + rb) << 3]);
        }
        __builtin_amdgcn_s_barrier();
        __builtin_amdgcn_s_setprio(1);
#pragma unroll
        for (int i = 0; i < 4; ++i)
#pragma unroll
            for (int j = 0; j < 2; ++j) {
                acc[i][j] = __builtin_amdgcn_mfma_f32_16x16x32_bf16(ah[i], bh[j], acc[i][j], 0, 0, 0);
                acc[i][j] = __builtin_amdgcn_mfma_f32_16x16x32_bf16(ah[i], bl[j], acc[i][j], 0, 0, 0);
                acc[i][j] = __builtin_amdgcn_mfma_f32_16x16x32_bf16(al[i], bh[j], acc[i][j], 0, 0, 0);
            }
        __builtin_amdgcn_s_setprio(0);
        __builtin_amdgcn_s_barrier();

        // ---- phase 1: read B-half1 (last reads of sB[cur]); MFMA (0..3)x(2..3)
#pragma unroll
        for (int j = 2; j < 4; ++j) {
            const int rb = wn * 64 + j * 16 + frow;
            bh[j] = *reinterpret_cast<const bf16x8*>(&sB[cur][0][(kg * 256 + rb) << 3]);
            bl[j] = *reinterpret_cast<const bf16x8*>(&sB[cur][1][(kg * 256 + rb) << 3]);
        }
        __builtin_amdgcn_s_barrier();       // all waves done reading sB[cur]
        __builtin_amdgcn_s_setprio(1);
#pragma unroll
        for (int i = 0; i < 4; ++i)
#pragma unroll
            for (int j = 2; j < 4; ++j) {
                acc[i][j] = __builtin_amdgcn_mfma_f32_16x16x32_bf16(ah[i], bh[j], acc[i][j], 0, 0, 0);
                acc[i][j] = __builtin_amdgcn_mfma_f32_16x16x32_bf16(ah[i], bl[j], acc[i][j], 0, 0, 0);
                acc[i][j] = __builtin_amdgcn_mfma_f32_16x16x32_bf16(al[i], bh[j], acc[i][j], 0, 0, 0);
            }
        __builtin_amdgcn_s_setprio(0);
        __builtin_amdgcn_s_barrier();

        // ---- phase 2: read A-half1 (last reads of sA[cur]); issue B(t+2)->sB[cur]
#pragma unroll
        for (int i = 0; i < 4; ++i) {
            const int ra = wm * 128 + (4 + i) * 16 + frow;
            ah[i] = *reinterpret_cast<const bf16x8*>(&sA[cur][0][(kg * 256 + ra) << 3]);
            al[i] = *reinterpret_cast<const bf16x8*>(&sA[cur][1][(kg * 256 + ra) << 3]);
        }
        if (pf2) stageB(cur, kt2);          // sB[cur] dead (barrier at end of p1)
        __builtin_amdgcn_s_barrier();       // all waves done reading sA[cur]
        __builtin_amdgcn_s_setprio(1);
#pragma unroll
        for (int i = 0; i < 4; ++i)
#pragma unroll
            for (int j = 0; j < 2; ++j) {
                acc[4 + i][j] = __builtin_amdgcn_mfma_f32_16x16x32_bf16(ah[i], bh[j], acc[4 + i][j], 0, 0, 0);
                acc[4 + i][j] = __builtin_amdgcn_mfma_f32_16x16x32_bf16(ah[i], bl[j], acc[4 + i][j], 0, 0, 0);
                acc[4 + i][j] = __builtin_amdgcn_mfma_f32_16x16x32_bf16(al[i], bh[j], acc[4 + i][j], 0, 0, 0);
            }
        __builtin_amdgcn_s_setprio(0);
        __builtin_amdgcn_s_barrier();

        // ---- phase 3: issue A(t+2)->sA[cur]; MFMA; counted wait (never 0 mid-loop)
        if (pf2) stageA(cur, kt2);          // sA[cur] dead (barrier at end of p2)
        __builtin_amdgcn_s_setprio(1);
#pragma unroll
        for (int i = 0; i < 4; ++i)
#pragma unroll
            for (int j = 2; j < 4; ++j) {
                acc[4 + i][j] = __builtin_amdgcn_mfma_f32_16x16x32_bf16(ah[i], bh[j], acc[4 + i][j], 0, 0, 0);
                acc[4 + i][j] = __builtin_amdgcn_mfma_f32_16x16x32_bf16(ah[i], bl[j], acc[4 + i][j], 0, 0, 0);
                acc[4 + i][j] = __builtin_amdgcn_mfma_f32_16x16x32_bf16(al[i], bh[j], acc[4 + i][j], 0, 0, 0);
            }
        __builtin_amdgcn_s_setprio(0);
        if (pf2) {
            // 8 newest = t+2's loads stay in flight; waits t+1's (4-6 phases old)
            asm volatile("s_waitcnt vmcnt(8)" ::: "memory");
        } else if (t + 1 < NT) {
            asm volatile("s_waitcnt vmcnt(0)" ::: "memory");   // drain t+1 (epilogue)
        }
        __builtin_amdgcn_s_barrier();
        cur ^= 1;
    }

    const int crow0 = m0 + wm * 128 + (lane >> 4) * 4;
    const int ccol0 = n0 + wn * 64 + (lane & 15);
#pragma unroll
    for (int mi = 0; mi < 8; ++mi)
#pragma unroll
        for (int ni = 0; ni < 4; ++ni)
#pragma unroll
            for (int r = 0; r < 4; ++r)
                Cz[(size_t)(crow0 + mi * 16 + r) * N + ccol0 + ni * 16] = acc[mi][ni][r];
}

// reduce 4 split-K partials (vectorized)
__global__ __launch_bounds__(256)
void reduce4_kernel(const float* __restrict__ p, float* __restrict__ o, int n4) {
    const int i = blockIdx.x * 256 + threadIdx.x;
    if (i >= n4) return;
    const int n = n4 * 4;
    const float4 a = reinterpret_cast<const float4*>(p)[i];
    const float4 b = *reinterpret_cast<const float4*>(&p[(size_t)n + i * 4]);
    const float4 c = *reinterpret_cast<const float4*>(&p[(size_t)2 * n + i * 4]);
    const float4 d = *reinterpret_cast<const float4*>(&p[(size_t)3 * n + i * 4]);
    float4 s;
    s.x = (a.x + b.x) + (c.x + d.x);
    s.y = (a.y + b.y) + (c.y + d.y);
    s.z = (a.z + b.z) + (c.z + d.z);
    s.w = (a.w + b.w) + (c.w + d.w);
    reinterpret_cast<float4*>(o)[i] = s;
}

// ---------------- fp32 vector GEMM ----------------
// MODE 0: plain. MODE 2: C = softplus(acc + 2*bias[m])  (bias per ROW)
template<int BM, int BN, int MODE>
__global__ __launch_bounds__(256)
void gemm_nt(const float* __restrict__ A, int lda,
             const float* __restrict__ W, int ldw,
             float* __restrict__ C, int ldc,
             int K, const float* __restrict__ bias) {
    constexpr int BK = 16;
    constexpr int TM = BM / 16;
    constexpr int TN = BN / 16;
    __shared__ float As[BK][BM];
    __shared__ float Ws[BK][BN];
    const int tid = threadIdx.x;
    const int tx = tid & 15;
    const int ty = tid >> 4;
    const int m0 = blockIdx.y * BM;
    const int n0 = blockIdx.x * BN;

    float acc[TM][TN];
#pragma unroll
    for (int i = 0; i < TM; ++i)
#pragma unroll
        for (int j = 0; j < TN; ++j) acc[i][j] = 0.0f;

    for (int kt = 0; kt < K; kt += BK) {
        for (int v = tid; v < BM * 4; v += 256) {
            const int row = v >> 2;
            const int kq  = (v & 3) << 2;
            const float4 t = *reinterpret_cast<const float4*>(
                &A[(size_t)(m0 + row) * lda + kt + kq]);
            As[kq + 0][row] = t.x; As[kq + 1][row] = t.y;
            As[kq + 2][row] = t.z; As[kq + 3][row] = t.w;
        }
        for (int v = tid; v < BN * 4; v += 256) {
            const int row = v >> 2;
            const int kq  = (v & 3) << 2;
            const float4 t = *reinterpret_cast<const float4*>(
                &W[(size_t)(n0 + row) * ldw + kt + kq]);
            Ws[kq + 0][row] = t.x; Ws[kq + 1][row] = t.y;
            Ws[kq + 2][row] = t.z; Ws[kq + 3][row] = t.w;
        }
        __syncthreads();
#pragma unroll
        for (int kk = 0; kk < BK; ++kk) {
            float a[TM], w[TN];
#pragma unroll
            for (int i = 0; i < TM; ++i) a[i] = As[kk][ty * TM + i];
#pragma unroll
            for (int j = 0; j < TN; ++j) w[j] = Ws[kk][tx * TN + j];
#pragma unroll
            for (int i = 0; i < TM; ++i)
#pragma unroll
                for (int j = 0; j < TN; ++j)
                    acc[i][j] = fmaf(a[i], w[j], acc[i][j]);
        }
        __syncthreads();
    }

#pragma unroll
    for (int i = 0; i < TM; ++i) {
        const size_t rowoff = (size_t)(m0 + ty * TM + i) * ldc + n0 + tx * TN;
        float bm = 0.f;
        if constexpr (MODE == 2) bm = 2.0f * bias[m0 + ty * TM + i];
#pragma unroll
        for (int j = 0; j < TN; ++j) {
            float v = acc[i][j];
            if constexpr (MODE == 2) v = softplus_f(v + bm);
            C[rowoff + j] = v;
        }
    }
}

// ---------------- split-K fp32 GEMM, A read from transposed xs_t ----------
template<int BM, int BN, int KSL>
__global__ __launch_bounds__(256)
void gemm_splitk_T(const float* __restrict__ At,
                   const float* __restrict__ W, int ldw,
                   float* __restrict__ pbuf, int ldc, int M) {
    constexpr int BK = 16;
    constexpr int TM = BM / 16;
    constexpr int TN = BN / 16;
    __shared__ float As[BK][BM];
    __shared__ float Ws[BK][BN];
    const int tid = threadIdx.x;
    const int tx = tid & 15;
    const int ty = tid >> 4;
    const int m0 = blockIdx.y * BM;
    const int n0 = blockIdx.x * BN;
    const int k0 = blockIdx.z * KSL;

    float acc[TM][TN];
#pragma unroll
    for (int i = 0; i < TM; ++i)
#pragma unroll
        for (int j = 0; j < TN; ++j) acc[i][j] = 0.0f;

    for (int kt = k0; kt < k0 + KSL; kt += BK) {
        for (int v = tid; v < BK * BM / 4; v += 256) {
            const int kk = v >> 5;
            const int m4 = (v & 31) << 2;
            *reinterpret_cast<float4*>(&As[kk][m4]) =
                *reinterpret_cast<const float4*>(&At[(size_t)(kt + kk) * M + m0 + m4]);
        }
        for (int v = tid; v < BN * 4; v += 256) {
            const int row = v >> 2;
            const int kq  = (v & 3) << 2;
            const float4 t = *reinterpret_cast<const float4*>(
                &W[(size_t)(n0 + row) * ldw + kt + kq]);
            Ws[kq + 0][row] = t.x; Ws[kq + 1][row] = t.y;
            Ws[kq + 2][row] = t.z; Ws[kq + 3][row] = t.w;
        }
        __syncthreads();
#pragma unroll
        for (int kk = 0; kk < BK; ++kk) {
            float a[TM], w[TN];
#pragma unroll
            for (int i = 0; i < TM; ++i) a[i] = As[kk][ty * TM + i];
#pragma unroll
            for (int j = 0; j < TN; ++j) w[j] = Ws[kk][tx * TN + j];
#pragma unroll
            for (int i = 0; i < TM; ++i)
#pragma unroll
                for (int j = 0; j < TN; ++j)
                    acc[i][j] = fmaf(a[i], w[j], acc[i][j]);
        }
        __syncthreads();
    }

    float* outp = pbuf + (size_t)blockIdx.z * M * ldc;
#pragma unroll
    for (int i = 0; i < TM; ++i) {
        const size_t rowoff = (size_t)(m0 + ty * TM + i) * ldc + n0 + tx * TN;
#pragma unroll
        for (int j = 0; j < TN; ++j) outp[rowoff + j] = acc[i][j];
    }
}

// reduce split-K partials; route dt-rank cols to xdbl, B/C cols to Bt/Ct
__global__ __launch_bounds__(256)
void reduce_bc(const float* __restrict__ pbuf, float* __restrict__ xdbl,
               float* __restrict__ Bt, float* __restrict__ Ct) {
    const int i = blockIdx.x * 256 + threadIdx.x;
    if (i >= M_ * 160) return;
    float s = 0.f;
#pragma unroll
    for (int z = 0; z < 16; ++z) s += pbuf[(size_t)z * M_ * 160 + i];
    const int bl = i / 160;
    const int c  = i - bl * 160;
    if (c < 128)      xdbl[i] = s;
    else if (c < 144) Bt[(size_t)(c - 128) * M_ + bl] = s;
    else              Ct[(size_t)(c - 144) * M_ + bl] = s;
}

// ---------------- conv + bias + silu, transposed output ----------------
__global__ __launch_bounds__(256)
void conv_silu_t(const float* __restrict__ xz, const float* __restrict__ cw,
                 const float* __restrict__ cb, float* __restrict__ xs_t) {
    __shared__ float tin[35][64];
    __shared__ float tout[64][33];
    const int d0 = blockIdx.x * 64;
    const int l0 = blockIdx.y * 32;
    const int b  = blockIdx.z;
    const int tid = threadIdx.x;

    for (int v = tid; v < 35 * 16; v += 256) {
        const int row = v >> 4;
        const int c4  = (v & 15) << 2;
        const int l = l0 - 3 + row;
        float4 t = {0.f, 0.f, 0.f, 0.f};
        if (l >= 0)
            t = *reinterpret_cast<const float4*>(
                &xz[(size_t)(b * L_ + l) * 2 * DI + d0 + c4]);
        *reinterpret_cast<float4*>(&tin[row][c4]) = t;
    }
    __syncthreads();

    const int dl = tid & 63;
    const int lq = tid >> 6;
    const float w0 = cw[(d0 + dl) * 4 + 0], w1 = cw[(d0 + dl) * 4 + 1];
    const float w2 = cw[(d0 + dl) * 4 + 2], w3 = cw[(d0 + dl) * 4 + 3];
    const float bias = cb[d0 + dl];
#pragma unroll
    for (int li = lq; li < 32; li += 4) {
        const float s = bias + tin[li][dl] * w0 + tin[li + 1][dl] * w1
                      + tin[li + 2][dl] * w2 + tin[li + 3][dl] * w3;
        tout[dl][li] = silu_f(s);
    }
    __syncthreads();

    for (int v = tid; v < 64 * 8; v += 256) {
        const int row = v >> 3;
        const int c4  = (v & 7) << 2;
        float4 t;
        t.x = tout[row][c4 + 0]; t.y = tout[row][c4 + 1];
        t.z = tout[row][c4 + 2]; t.w = tout[row][c4 + 3];
        *reinterpret_cast<float4*>(&xs_t[(size_t)(d0 + row) * M_ + b * L_ + l0 + c4]) = t;
    }
}

// ---------------- scan phase 1 ----------------
__global__ __launch_bounds__(256)
void scan_phase1(const float* __restrict__ dt_t, const float* __restrict__ xs_t,
                 const float* __restrict__ Bt, const float* __restrict__ alog,
                 float* __restrict__ sfin, float* __restrict__ aprod) {
    const int c    = blockIdx.x & 15;
    const int dblk = (blockIdx.x >> 4) & 255;
    const int b    = blockIdx.x >> 12;
    const int tid  = threadIdx.x;
    const int n  = tid & 15;
    const int dg = tid >> 4;
    const int d  = dblk * 16 + dg;

    const float Av = -expf(alog[d * DS + n]);
    const size_t rowoff = (size_t)d * M_ + b * L_ + c * LC;
    const float* dtp = dt_t + rowoff;
    const float* xsp = xs_t + rowoff;
    const float* Bp  = Bt + (size_t)n * M_ + b * L_ + c * LC;

    float s = 0.f, dts = 0.f;
#pragma unroll 4
    for (int l = 0; l < LC; l += 4) {
        const float4 dt4 = *reinterpret_cast<const float4*>(dtp + l);
        const float4 x4  = *reinterpret_cast<const float4*>(xsp + l);
        const float4 b4  = *reinterpret_cast<const float4*>(Bp + l);
        s = fmaf(__expf(dt4.x * Av), s, dt4.x * b4.x * x4.x); dts += dt4.x;
        s = fmaf(__expf(dt4.y * Av), s, dt4.y * b4.y * x4.y); dts += dt4.y;
        s = fmaf(__expf(dt4.z * Av), s, dt4.z * b4.z * x4.z); dts += dt4.z;
        s = fmaf(__expf(dt4.w * Av), s, dt4.w * b4.w * x4.w); dts += dt4.w;
    }
    const size_t o = (size_t)c * NCHAIN + ((size_t)(b * DI + d)) * DS + n;
    sfin[o]  = s;
    aprod[o] = __expf(Av * dts);
}

// ---------------- scan phase 2 ----------------
__global__ __launch_bounds__(256)
void scan_phase2(const float* __restrict__ sfin, const float* __restrict__ aprod,
                 float* __restrict__ prefix) {
    const int t = blockIdx.x * 256 + threadIdx.x;
    float p = 0.f;
#pragma unroll
    for (int c = 0; c < NCH; ++c) {
        const size_t o = (size_t)c * NCHAIN + t;
        prefix[o] = p;
        p = fmaf(aprod[o], p, sfin[o]);
    }
}

// ---------------- scan phase 3 ----------------
__global__ __launch_bounds__(256)
void scan_phase3(const float* __restrict__ dt_t, const float* __restrict__ xs_t,
                 const float* __restrict__ Bt, const float* __restrict__ Ct,
                 const float* __restrict__ alog, const float* __restrict__ Dp,
                 const float* __restrict__ prefix, float* __restrict__ ybuf) {
    const int c    = blockIdx.x & 15;
    const int dblk = (blockIdx.x >> 4) & 255;
    const int b    = blockIdx.x >> 12;
    const int tid  = threadIdx.x;
    const int n  = tid & 15;
    const int dg = tid >> 4;
    const int d  = dblk * 16 + dg;

    const float Av = -expf(alog[d * DS + n]);
    const float Dv = Dp[d];
    float s = prefix[(size_t)c * NCHAIN + ((size_t)(b * DI + d)) * DS + n];

    const size_t rowoff = (size_t)d * M_ + b * L_ + c * LC;
    const float* dtp = dt_t + rowoff;
    const float* xsp = xs_t + rowoff;
    const float* Bp  = Bt + (size_t)n * M_ + b * L_ + c * LC;
    const float* Cp  = Ct + (size_t)n * M_ + b * L_ + c * LC;
    float* yout = ybuf + (size_t)(b * L_ + c * LC) * DI + d;

#pragma unroll 2
    for (int l = 0; l < LC; l += 4) {
        const float4 dt4 = *reinterpret_cast<const float4*>(dtp + l);
        const float4 x4  = *reinterpret_cast<const float4*>(xsp + l);
        const float4 b4  = *reinterpret_cast<const float4*>(Bp + l);
        const float4 c4  = *reinterpret_cast<const float4*>(Cp + l);
#pragma unroll
        for (int k = 0; k < 4; ++k) {
            const float dt = (k == 0) ? dt4.x : (k == 1) ? dt4.y : (k == 2) ? dt4.z : dt4.w;
            const float x  = (k == 0) ? x4.x  : (k == 1) ? x4.y  : (k == 2) ? x4.z  : x4.w;
            const float Bv = (k == 0) ? b4.x  : (k == 1) ? b4.y  : (k == 2) ? b4.z  : b4.w;
            const float Cv = (k == 0) ? c4.x  : (k == 1) ? c4.y  : (k == 2) ? c4.z  : c4.w;
            s = fmaf(__expf(dt * Av), s, dt * Bv * x);
            float contrib = s * Cv;
            contrib += __shfl_xor(contrib, 1);
            contrib += __shfl_xor(contrib, 2);
            contrib += __shfl_xor(contrib, 4);
            contrib += __shfl_xor(contrib, 8);
            if (n == 0) yout[(size_t)(l + k) * DI] = fmaf(x, Dv, contrib);
        }
    }
}

extern "C" void kernel_launch(void* const* d_in, const int* in_sizes, int n_in,
                              void* d_out, int out_size, void* d_ws, size_t ws_size,
                              hipStream_t stream) {
    const float* hs   = (const float*)d_in[0];
    const float* ipw  = (const float*)d_in[1];
    const float* cw   = (const float*)d_in[2];
    const float* cb   = (const float*)d_in[3];
    const float* xpw  = (const float*)d_in[4];
    const float* dpw  = (const float*)d_in[5];
    const float* dpb  = (const float*)d_in[6];
    const float* alog = (const float*)d_in[7];
    const float* Dp   = (const float*)d_in[8];
    const float* opw  = (const float*)d_in[9];
    float* out = (float*)d_out;

    float* ws    = (float*)d_ws;
    float* xz    = ws;                              // 16,777,216 f
    float* xs_t  = xz   + (size_t)16777216;         //  8,388,608 f
    float* xdbl  = xs_t + (size_t)8388608;          //    327,680 f
    float* ybuf  = xdbl + (size_t)327680;           //  8,388,608 f
    float* Bt    = ybuf + (size_t)8388608;          //     32,768 f
    float* Ct    = Bt   + (size_t)32768;            //     32,768 f
    float* R     = Ct   + (size_t)32768;

    // R: scan view
    float* dt_t  = R;                               // 8,388,608 f
    float* sfin  = R + (size_t)8388608;             // 2,097,152 f
    float* aprd  = sfin + (size_t)2097152;
    float* pref  = aprd + (size_t)2097152;
    float* pbuf  = dt_t;                            // splitk partials (x_proj)
    // R: phase-1 split view (dead after GEMM1)
    short* hs_hi  = (short*)R;
    short* hs_lo  = hs_hi + (size_t)M_ * DM;
    short* ipw_hi = hs_lo + (size_t)M_ * DM;
    short* ipw_lo = ipw_hi + (size_t)2 * DI * DM;
    // R: phase-2 split view (written after scan dies)
    short* yg_hi  = (short*)R;
    short* yg_lo  = yg_hi + (size_t)M_ * DI;
    short* opw_hi = yg_lo + (size_t)M_ * DI;
    short* opw_lo = opw_hi + (size_t)DM * DI;
    // GEMM6 split-K partials: xz region (dead after split_gate)
    float* pbuf6  = xz;                             // 4 * 2048 * 2048 f

    // 1) xz = hs @ in_proj_w^T  (split-bf16, 256x256 counted-vmcnt MFMA)
    split_bf16_kernel<<<(M_ * DM / 4 + 255) / 256, 256, 0, stream>>>(hs, hs_hi, hs_lo, M_ * DM / 4);
    split_bf16_kernel<<<(2 * DI * DM / 4 + 255) / 256, 256, 0, stream>>>(ipw, ipw_hi, ipw_lo, 2 * DI * DM / 4);
    gemm256_split<1><<<dim3(2 * DI / 256, M_ / 256, 1), 512, 0, stream>>>(
        hs_hi, hs_lo, ipw_hi, ipw_lo, xz, M_, 2 * DI, DM);

    // 2) conv + silu -> xs_t directly (transposed)
    conv_silu_t<<<dim3(DI / 64, L_ / 32, B_), 256, 0, stream>>>(xz, cw, cb, xs_t);

    // 3) x_dbl = x_silu @ x_proj_w^T  (split-K from xs_t; reduce routes B/C)
    gemm_splitk_T<128, 32, 256><<<dim3(160 / 32, M_ / 128, 16), 256, 0, stream>>>(
        xs_t, xpw, DI, pbuf, 160, M_);
    reduce_bc<<<(M_ * 160 + 255) / 256, 256, 0, stream>>>(pbuf, xdbl, Bt, Ct);

    // 4) dt_t[d][bl] = softplus(dpw @ xdbl^T + 2*dpb)
    gemm_nt<128, 128, 2><<<dim3(M_ / 128, DI / 128), 256, 0, stream>>>(
        dpw, DR, xdbl, 160, dt_t, M_, DR, dpb);

    // 5) chunked scan
    scan_phase1<<<B_ * 256 * NCH, 256, 0, stream>>>(dt_t, xs_t, Bt, alog, sfin, aprd);
    scan_phase2<<<NCHAIN / 256, 256, 0, stream>>>(sfin, aprd, pref);
    scan_phase3<<<B_ * 256 * NCH, 256, 0, stream>>>(dt_t, xs_t, Bt, Ct, alog, Dp, pref, ybuf);

    // 6) out = (y*z) @ out_proj_w^T  (split-bf16, 256x256 split-K x4)
    split_gate_kernel<<<(M_ * DI / 4) / 256, 256, 0, stream>>>(ybuf, xz, yg_hi, yg_lo);
    split_bf16_kernel<<<(DM * DI / 4 + 255) / 256, 256, 0, stream>>>(opw, opw_hi, opw_lo, DM * DI / 4);
    gemm256_split<4><<<dim3(DM / 256, M_ / 256, 4), 512, 0, stream>>>(
        yg_hi, yg_lo, opw_hi, opw_lo, pbuf6, M_, DM, DI);
    reduce4_kernel<<<(M_ * DM / 4 + 255) / 256, 256, 0, stream>>>(pbuf6, out, M_ * DM / 4);
}